// Round 10
// baseline (495.112 us; speedup 1.0000x reference)
//
#include <hip/hip_runtime.h>
#include <hip/hip_bf16.h>
#include <stdint.h>

#define NN 200000
#define NE 800000
#define FIN 128
#define NG 8000
#define EPSV 1e-5f
#define NBS ((NN + 255) / 256)   // 782 scan blocks
#define CNT_B (NE / 256)         // 3125 (exact)

typedef __attribute__((ext_vector_type(8))) short bf16x8;   // 8 bf16 = 4 VGPRs
typedef __attribute__((ext_vector_type(4))) float f32x4;    // MFMA C/D

static __device__ __forceinline__ bf16x8 as_bf16x8(uint4 u) {
    union { uint4 u; bf16x8 v; } c; c.u = u; return c.v;
}

// bf16 helpers: load-convert (exact) and pack with RNE
static __device__ __forceinline__ void u2f(uint4 v, float4& lo, float4& hi) {
    lo.x = __uint_as_float(v.x << 16); lo.y = __uint_as_float(v.x & 0xffff0000u);
    lo.z = __uint_as_float(v.y << 16); lo.w = __uint_as_float(v.y & 0xffff0000u);
    hi.x = __uint_as_float(v.z << 16); hi.y = __uint_as_float(v.z & 0xffff0000u);
    hi.z = __uint_as_float(v.w << 16); hi.w = __uint_as_float(v.w & 0xffff0000u);
}
static __device__ __forceinline__ unsigned int pk(float a, float b) {
    __hip_bfloat16 x = __float2bfloat16(a), y = __float2bfloat16(b);
    return (unsigned int)(*(unsigned short*)&x) | ((unsigned int)(*(unsigned short*)&y) << 16);
}

// ---- prep1: [0,3125) edge-count histogram | [3125,3907) graph starts | [3907,3939) W3 split ----
__global__ __launch_bounds__(256) void k_prep1(const int* __restrict__ dst, int* __restrict__ cnt,
                                               const int* __restrict__ batch, int* __restrict__ startg,
                                               const float* __restrict__ W3,
                                               unsigned short* __restrict__ whi,
                                               unsigned short* __restrict__ wlo) {
    int b = blockIdx.x, t = threadIdx.x;
    if (b < CNT_B) {
        int e = b * 256 + t;
        atomicAdd(&cnt[dst[e]], 1);
    } else if (b < CNT_B + NBS) {
        int n = (b - CNT_B) * 256 + t;
        if (n >= NN) return;
        int bb = batch[n];
        int prev = (n == 0) ? -1 : batch[n - 1];
        for (int g = prev + 1; g <= bb; ++g) startg[g] = n;
        if (n == NN - 1) {
            for (int g = bb + 1; g <= NG; ++g) startg[g] = NN;
        }
    } else {
        int i = (b - CNT_B - NBS) * 256 + t;   // 8192 elems
        if (i >= 64 * 128) return;
        int n = i >> 6, k = i & 63;
        float w = W3[k * 128 + n];
        __hip_bfloat16 h = __float2bfloat16(w);
        float hf = __bfloat162float(h);
        __hip_bfloat16 l = __float2bfloat16(w - hf);
        whi[n * 64 + k] = *(unsigned short*)&h;
        wlo[n * 64 + k] = *(unsigned short*)&l;
    }
}

// ---- per-256-chunk sums ----
__global__ void k_blocksum(const int* __restrict__ cnt, int* __restrict__ bsum) {
    __shared__ int sh[256];
    int b = blockIdx.x, t = threadIdx.x;
    int idx = b * 256 + t;
    sh[t] = (idx < NN) ? cnt[idx] : 0;
    __syncthreads();
    for (int o = 128; o > 0; o >>= 1) {
        if (t < o) sh[t] += sh[t + o];
        __syncthreads();
    }
    if (t == 0) bsum[b] = sh[0];
}

// ---- single-block scan of chunk sums -> exclusive prefixes ----
__global__ __launch_bounds__(1024) void k_scanb(const int* __restrict__ bsum, int* __restrict__ bpre) {
    __shared__ int sh[1024];
    int t = threadIdx.x;
    int v = (t < NBS) ? bsum[t] : 0;
    sh[t] = v;
    __syncthreads();
    for (int o = 1; o < 1024; o <<= 1) {
        int add = (t >= o) ? sh[t - o] : 0;
        __syncthreads();
        sh[t] += add;
        __syncthreads();
    }
    if (t < NBS) bpre[t] = sh[t] - v;  // exclusive
}

// ---- per-chunk scan + offset -> rowstart/cursor; dis = rsqrt(1+deg) in place ----
__global__ void k_scanchunk(int* __restrict__ cnt, const int* __restrict__ bpre,
                            int* __restrict__ rowstart, int* __restrict__ cursor) {
    __shared__ int sh[256];
    int b = blockIdx.x, t = threadIdx.x;
    int idx = b * 256 + t;
    int v = (idx < NN) ? cnt[idx] : 0;
    sh[t] = v;
    __syncthreads();
    for (int o = 1; o < 256; o <<= 1) {
        int add = (t >= o) ? sh[t - o] : 0;
        __syncthreads();
        sh[t] += add;
        __syncthreads();
    }
    if (idx < NN) {
        int rs = bpre[b] + sh[t] - v;
        rowstart[idx] = rs;
        cursor[idx] = rs;
        ((float*)cnt)[idx] = rsqrtf(1.0f + (float)v);  // cnt -> dis in place
    }
    if (idx == 0) rowstart[NN] = NE;
}

// ---- per-graph instance-norm stats, latency-tolerant: 8 node slots x 32 float4 lanes ----
__global__ __launch_bounds__(256) void k_stats2(const float* __restrict__ x,
                                                const int* __restrict__ startg,
                                                const float* __restrict__ nw,
                                                const float* __restrict__ nb,
                                                float* __restrict__ scale,
                                                float* __restrict__ shift) {
    __shared__ float4 rsum[256], rsq[256];
    int g = blockIdx.x;
    int s = startg[g], e = startg[g + 1];
    if (s == e) return;
    int t = threadIdx.x;
    int slot = t >> 5, c4 = t & 31;
    const float4* x4 = (const float4*)x;
    float4 sum = {0.f, 0.f, 0.f, 0.f}, sq = {0.f, 0.f, 0.f, 0.f};
    for (int n = s + slot; n < e; n += 8) {
        float4 v = x4[n * 32 + c4];
        sum.x += v.x; sum.y += v.y; sum.z += v.z; sum.w += v.w;
        sq.x += v.x * v.x; sq.y += v.y * v.y; sq.z += v.z * v.z; sq.w += v.w * v.w;
    }
    rsum[slot * 32 + c4] = sum;
    rsq[slot * 32 + c4] = sq;
    __syncthreads();
    if (t < 32) {
        float4 S = rsum[t], Q = rsq[t];
#pragma unroll
        for (int sl = 1; sl < 8; ++sl) {
            float4 a = rsum[sl * 32 + t], bq = rsq[sl * 32 + t];
            S.x += a.x; S.y += a.y; S.z += a.z; S.w += a.w;
            Q.x += bq.x; Q.y += bq.y; Q.z += bq.z; Q.w += bq.w;
        }
        float inv = 1.0f / (float)(e - s);
        float w = nw[0], bb = nb[0];
        float4 sc, sh;
        {
            float m = S.x * inv, v = fmaxf(Q.x * inv - m * m, 0.f);
            float is = rsqrtf(v + EPSV); sc.x = is * w; sh.x = bb - m * is * w;
        }
        {
            float m = S.y * inv, v = fmaxf(Q.y * inv - m * m, 0.f);
            float is = rsqrtf(v + EPSV); sc.y = is * w; sh.y = bb - m * is * w;
        }
        {
            float m = S.z * inv, v = fmaxf(Q.z * inv - m * m, 0.f);
            float is = rsqrtf(v + EPSV); sc.z = is * w; sh.z = bb - m * is * w;
        }
        {
            float m = S.w * inv, v = fmaxf(Q.w * inv - m * m, 0.f);
            float is = rsqrtf(v + EPSV); sc.w = is * w; sh.w = bb - m * is * w;
        }
        ((float4*)scale)[g * 32 + t] = sc;
        ((float4*)shift)[g * 32 + t] = sh;
    }
}

// ---- conv1 + CSR fill, interleaved grid (even: conv1 64-node tile; odd: fill 256 edges).
//      Fill's latency-bound scattered atomics/writes hide under conv1's VALU+LDS work. ----
__global__ __launch_bounds__(256) void k_conv1f(const float* __restrict__ x,
                                                const int* __restrict__ batch,
                                                const float* __restrict__ scale,
                                                const float* __restrict__ shift,
                                                const float* __restrict__ W1,
                                                const float* __restrict__ dis,
                                                float* __restrict__ p1,
                                                const int* __restrict__ src,
                                                const int* __restrict__ dst,
                                                int* __restrict__ cursor,
                                                int* __restrict__ csr) {
    __shared__ float4 sx4[64 * 33];   // row stride 33 f4 (132 dwords = 4 mod 32: conflict-free)
    int t = threadIdx.x;
    if (blockIdx.x & 1) {             // fill half
        int e = (blockIdx.x >> 1) * 256 + t;
        int pos = atomicAdd(&cursor[dst[e]], 1);
        csr[pos] = src[e];
        return;
    }
    int base = (blockIdx.x >> 1) * 64;    // NN % 64 == 0
    const float4* x4 = (const float4*)x;
    const float4* sc4 = (const float4*)scale;
    const float4* sh4 = (const float4*)shift;
    for (int i = t; i < 64 * 32; i += 256) {
        int nl = i >> 5, c4 = i & 31;
        int n = base + nl;
        int g = batch[n];
        float4 xv = x4[n * 32 + c4];
        float4 sc = sc4[g * 32 + c4];
        float4 sh = sh4[g * 32 + c4];
        float4 r;
        r.x = fmaf(xv.x, sc.x, sh.x);
        r.y = fmaf(xv.y, sc.y, sh.y);
        r.z = fmaf(xv.z, sc.z, sh.z);
        r.w = fmaf(xv.w, sc.w, sh.w);
        sx4[nl * 33 + c4] = r;
    }
    __syncthreads();
    int lane = t & 63;
    int kq = __builtin_amdgcn_readfirstlane(t >> 6) * 2;  // f4 column index (k0 = kq*4)
    const float4* W4 = (const float4*)W1;                 // [128 rows][8 f4]
    const float4* arow = &sx4[lane * 33];
    float4 acc0 = {0.f, 0.f, 0.f, 0.f}, acc1 = {0.f, 0.f, 0.f, 0.f};
#pragma unroll 4
    for (int c4 = 0; c4 < 32; ++c4) {
        float4 a = arow[c4];
        int rb = c4 * 32 + kq;        // rows 4*c4 .. 4*c4+3, cols kq,kq+1
        float4 wA0 = W4[rb +  0], wA1 = W4[rb +  1];
        float4 wB0 = W4[rb +  8], wB1 = W4[rb +  9];
        float4 wC0 = W4[rb + 16], wC1 = W4[rb + 17];
        float4 wD0 = W4[rb + 24], wD1 = W4[rb + 25];
        acc0.x += a.x * wA0.x + a.y * wB0.x + a.z * wC0.x + a.w * wD0.x;
        acc0.y += a.x * wA0.y + a.y * wB0.y + a.z * wC0.y + a.w * wD0.y;
        acc0.z += a.x * wA0.z + a.y * wB0.z + a.z * wC0.z + a.w * wD0.z;
        acc0.w += a.x * wA0.w + a.y * wB0.w + a.z * wC0.w + a.w * wD0.w;
        acc1.x += a.x * wA1.x + a.y * wB1.x + a.z * wC1.x + a.w * wD1.x;
        acc1.y += a.x * wA1.y + a.y * wB1.y + a.z * wC1.y + a.w * wD1.y;
        acc1.z += a.x * wA1.z + a.y * wB1.z + a.z * wC1.z + a.w * wD1.z;
        acc1.w += a.x * wA1.w + a.y * wB1.w + a.z * wC1.w + a.w * wD1.w;
    }
    int n = base + lane;
    float d = dis[n];
    float4 r0, r1;
    r0.x = acc0.x * d; r0.y = acc0.y * d; r0.z = acc0.z * d; r0.w = acc0.w * d;
    r1.x = acc1.x * d; r1.y = acc1.y * d; r1.z = acc1.z * d; r1.w = acc1.w * d;
    ((float4*)p1)[n * 8 + kq] = r0;
    ((float4*)p1)[n * 8 + kq + 1] = r1;
}

// ---- gather1 (C=32, float4) + conv1 epilogue: p2 = relu(dis*(self+neigh)+b1)*dis ----
__global__ __launch_bounds__(256) void k_gather1(const float* __restrict__ p1,
                                                 const int* __restrict__ rowstart,
                                                 const int* __restrict__ csr,
                                                 const float* __restrict__ dis,
                                                 const float* __restrict__ b1,
                                                 float* __restrict__ p2) {
    int tid = blockIdx.x * 256 + threadIdx.x;  // NN*8 threads
    int n = tid >> 3, c4 = tid & 7;
    const float4* p1_4 = (const float4*)p1;
    int s = rowstart[n], e = rowstart[n + 1];
    float4 agg = p1_4[n * 8 + c4];  // self-loop (p = h*dis already)
    int j = s;
    for (; j + 1 < e; j += 2) {
        float4 v0 = p1_4[csr[j] * 8 + c4];
        float4 v1 = p1_4[csr[j + 1] * 8 + c4];
        agg.x += v0.x + v1.x; agg.y += v0.y + v1.y;
        agg.z += v0.z + v1.z; agg.w += v0.w + v1.w;
    }
    if (j < e) {
        float4 v = p1_4[csr[j] * 8 + c4];
        agg.x += v.x; agg.y += v.y; agg.z += v.z; agg.w += v.w;
    }
    float d = dis[n];
    float4 bb = ((const float4*)b1)[c4];
    float4 r;
    r.x = fmaxf(d * agg.x + bb.x, 0.f) * d;
    r.y = fmaxf(d * agg.y + bb.y, 0.f) * d;
    r.z = fmaxf(d * agg.z + bb.z, 0.f) * d;
    r.w = fmaxf(d * agg.w + bb.w, 0.f) * d;
    ((float4*)p2)[n * 8 + c4] = r;
}

// ---- fused gather2 + conv2: p3(bf16) = relu((dis*(self+neigh))@W2 + b2)*dis  [32->64] ----
__global__ __launch_bounds__(256) void k_conv2g(const float* __restrict__ p2,
                                                const int* __restrict__ rowstart,
                                                const int* __restrict__ csr,
                                                const float* __restrict__ dis,
                                                const float* __restrict__ W2,
                                                const float* __restrict__ b2v,
                                                __hip_bfloat16* __restrict__ p3h) {
    __shared__ float sW[32 * 64];        // 8 KB
    __shared__ float4 spart[16 * 16];    // 4 KB
    __shared__ float sa[16 * 32];        // 2 KB
    int t = threadIdx.x;
    const float4* W4 = (const float4*)W2;
    for (int i = t; i < 32 * 64 / 4; i += 256) ((float4*)sW)[i] = W4[i];
    int base = blockIdx.x * 16;
    const float4* p2_4 = (const float4*)p2;
    {
        int node = t >> 4, c4 = t & 7, half = (t >> 3) & 1;
        int n = base + node;
        int s = rowstart[n], e = rowstart[n + 1];
        float4 agg = {0.f, 0.f, 0.f, 0.f};
        if (half == 0) {
            agg = p2_4[n * 8 + c4];  // self
            for (int j = s; j < e; j += 2) {
                float4 v = p2_4[csr[j] * 8 + c4];
                agg.x += v.x; agg.y += v.y; agg.z += v.z; agg.w += v.w;
            }
        } else {
            for (int j = s + 1; j < e; j += 2) {
                float4 v = p2_4[csr[j] * 8 + c4];
                agg.x += v.x; agg.y += v.y; agg.z += v.z; agg.w += v.w;
            }
        }
        spart[node * 16 + half * 8 + c4] = agg;
    }
    __syncthreads();
    if (t < 128) {
        int nd = t >> 3, cc = t & 7;
        float4 a = spart[nd * 16 + cc], b = spart[nd * 16 + 8 + cc];
        float d = dis[base + nd];
        float4 r;
        r.x = d * (a.x + b.x); r.y = d * (a.y + b.y);
        r.z = d * (a.z + b.z); r.w = d * (a.w + b.w);
        ((float4*)sa)[nd * 8 + cc] = r;
    }
    __syncthreads();
    int k = t & 63, grp = t >> 6;
    float acc[4] = {0.f, 0.f, 0.f, 0.f};
    for (int c = 0; c < 32; ++c) {
        float w = sW[c * 64 + k];
#pragma unroll
        for (int q = 0; q < 4; ++q) acc[q] += sa[(grp * 4 + q) * 32 + c] * w;
    }
    float bb = b2v[k];
#pragma unroll
    for (int q = 0; q < 4; ++q) {
        int n = base + grp * 4 + q;
        float h = fmaxf(acc[q] + bb, 0.f);
        p3h[n * 64 + k] = __float2bfloat16(h * dis[n]);
    }
}

// ---- conv3: fused edge-gather -> LDS -> MFMA -> low-atomic pool. ----
__global__ __launch_bounds__(256) void k_conv3mg(const __hip_bfloat16* __restrict__ p3h,
                                                 const int* __restrict__ rowstart,
                                                 const int* __restrict__ csr,
                                                 const float* __restrict__ dis,
                                                 const unsigned short* __restrict__ w3hi,
                                                 const unsigned short* __restrict__ w3lo,
                                                 const float* __restrict__ b3v,
                                                 const int* __restrict__ batch,
                                                 unsigned int* __restrict__ pooled) {
    __shared__ uint4 sa[64 * 9];     // 9.2 KB; dead after MFMA -> reused as spool (8 KB)
    __shared__ float sp[64 * 132];   // 33.8 KB, row stride 132 floats (pad)
    __shared__ int sbatch[64];
    int t = threadIdx.x;
    int base = blockIdx.x * 64;
    if (t < 64) sbatch[t] = batch[base + t];
    const uint4* p3q = (const uint4*)p3h;
    // fused gather3: 512 (node, c8) tasks, 2 per thread
    for (int i = t; i < 64 * 8; i += 256) {
        int nl = i >> 3, c8 = i & 7;
        int n = base + nl;
        int s = rowstart[n], e = rowstart[n + 1];
        float4 alo, ahi;
        u2f(p3q[n * 8 + c8], alo, ahi);  // self
        int j = s;
        for (; j + 1 < e; j += 2) {
            float4 l0, h0, l1, h1;
            u2f(p3q[csr[j] * 8 + c8], l0, h0);
            u2f(p3q[csr[j + 1] * 8 + c8], l1, h1);
            alo.x += l0.x + l1.x; alo.y += l0.y + l1.y;
            alo.z += l0.z + l1.z; alo.w += l0.w + l1.w;
            ahi.x += h0.x + h1.x; ahi.y += h0.y + h1.y;
            ahi.z += h0.z + h1.z; ahi.w += h0.w + h1.w;
        }
        if (j < e) {
            float4 l0, h0;
            u2f(p3q[csr[j] * 8 + c8], l0, h0);
            alo.x += l0.x; alo.y += l0.y; alo.z += l0.z; alo.w += l0.w;
            ahi.x += h0.x; ahi.y += h0.y; ahi.z += h0.z; ahi.w += h0.w;
        }
        float d = dis[n];
        uint4 o;
        o.x = pk(d * alo.x, d * alo.y);
        o.y = pk(d * alo.z, d * alo.w);
        o.z = pk(d * ahi.x, d * ahi.y);
        o.w = pk(d * ahi.z, d * ahi.w);
        sa[nl * 9 + c8] = o;
    }
    __syncthreads();
    int lane = t & 63, w = t >> 6;
    int h = lane >> 4;        // k-group 0..3 (k = kt*32 + h*8 + j)
    int cid = lane & 15;      // row (A) / col (B,C) within 16
    const uint4* WHq = (const uint4*)w3hi;   // [128 ch][8 granules]
    const uint4* WLq = (const uint4*)w3lo;
    uint4 bh[2][2], bl[2][2];
#pragma unroll
    for (int nl = 0; nl < 2; ++nl) {
        int n = (w * 2 + nl) * 16 + cid;
#pragma unroll
        for (int kt = 0; kt < 2; ++kt) {
            bh[nl][kt] = WHq[n * 8 + kt * 4 + h];
            bl[nl][kt] = WLq[n * 8 + kt * 4 + h];
        }
    }
    f32x4 acc[2][4];
#pragma unroll
    for (int nl = 0; nl < 2; ++nl)
#pragma unroll
        for (int mi = 0; mi < 4; ++mi) acc[nl][mi] = {0.f, 0.f, 0.f, 0.f};
#pragma unroll
    for (int mi = 0; mi < 4; ++mi) {
        int arow = (mi * 16 + cid) * 9;
        bf16x8 a0 = as_bf16x8(sa[arow + h]);        // kt=0
        bf16x8 a1 = as_bf16x8(sa[arow + 4 + h]);    // kt=1
#pragma unroll
        for (int nl = 0; nl < 2; ++nl) {
            acc[nl][mi] = __builtin_amdgcn_mfma_f32_16x16x32_bf16(a0, as_bf16x8(bh[nl][0]), acc[nl][mi], 0, 0, 0);
            acc[nl][mi] = __builtin_amdgcn_mfma_f32_16x16x32_bf16(a1, as_bf16x8(bh[nl][1]), acc[nl][mi], 0, 0, 0);
            acc[nl][mi] = __builtin_amdgcn_mfma_f32_16x16x32_bf16(a0, as_bf16x8(bl[nl][0]), acc[nl][mi], 0, 0, 0);
            acc[nl][mi] = __builtin_amdgcn_mfma_f32_16x16x32_bf16(a1, as_bf16x8(bl[nl][1]), acc[nl][mi], 0, 0, 0);
        }
    }
    // epilogue: bias + relu -> sp[node][ch]
#pragma unroll
    for (int nl = 0; nl < 2; ++nl) {
        int ch = (w * 2 + nl) * 16 + cid;
        float bb = b3v[ch];
#pragma unroll
        for (int mi = 0; mi < 4; ++mi) {
#pragma unroll
            for (int r = 0; r < 4; ++r) {
                int node_l = mi * 16 + h * 4 + r;
                sp[node_l * 132 + ch] = fmaxf(acc[nl][mi][r] + bb, 0.f);
            }
        }
    }
    __syncthreads();
    // Phase C: init interior-graph pool (reuse sa: 16 slots x 128 ch of uint)
    unsigned int* spool = (unsigned int*)sa;
    for (int i = t; i < 16 * 128; i += 256) spool[i] = 0u;
    __syncthreads();
    int g0 = sbatch[0], g63 = sbatch[63];
    // Phase D: run-length pool; interior -> LDS atomic, boundary/overflow -> global
    int k4 = t & 31, n0 = (t >> 5) * 8;
    int curg = sbatch[n0];
    float4 cm = {0.f, 0.f, 0.f, 0.f};
#pragma unroll
    for (int ii = 0; ii < 8; ++ii) {
        int g = sbatch[n0 + ii];
        float4 hv = *(const float4*)&sp[(n0 + ii) * 132 + k4 * 4];
        if (g != curg) {
            int s = curg - g0 - 1;
            if (s >= 0 && curg < g63 && s < 16) {
                unsigned int* d = spool + s * 128 + k4 * 4;
                atomicMax(d + 0, __float_as_uint(cm.x));
                atomicMax(d + 1, __float_as_uint(cm.y));
                atomicMax(d + 2, __float_as_uint(cm.z));
                atomicMax(d + 3, __float_as_uint(cm.w));
            } else {
                unsigned int* d = pooled + curg * 128 + k4 * 4;
                atomicMax(d + 0, __float_as_uint(cm.x));
                atomicMax(d + 1, __float_as_uint(cm.y));
                atomicMax(d + 2, __float_as_uint(cm.z));
                atomicMax(d + 3, __float_as_uint(cm.w));
            }
            cm = {0.f, 0.f, 0.f, 0.f};
            curg = g;
        }
        cm.x = fmaxf(cm.x, hv.x);
        cm.y = fmaxf(cm.y, hv.y);
        cm.z = fmaxf(cm.z, hv.z);
        cm.w = fmaxf(cm.w, hv.w);
    }
    {
        int s = curg - g0 - 1;
        if (s >= 0 && curg < g63 && s < 16) {
            unsigned int* d = spool + s * 128 + k4 * 4;
            atomicMax(d + 0, __float_as_uint(cm.x));
            atomicMax(d + 1, __float_as_uint(cm.y));
            atomicMax(d + 2, __float_as_uint(cm.z));
            atomicMax(d + 3, __float_as_uint(cm.w));
        } else {
            unsigned int* d = pooled + curg * 128 + k4 * 4;
            atomicMax(d + 0, __float_as_uint(cm.x));
            atomicMax(d + 1, __float_as_uint(cm.y));
            atomicMax(d + 2, __float_as_uint(cm.z));
            atomicMax(d + 3, __float_as_uint(cm.w));
        }
    }
    __syncthreads();
    // Phase E: interior graphs have this block as sole writer -> plain float4 stores
    {
        int s = t >> 4;              // slot 0..15
        int g = g0 + 1 + s;
        if (g < g63) {
            int ch = (t & 15) * 8;
            const float* spf = (const float*)spool;
            float4 v0 = *(const float4*)&spf[s * 128 + ch];
            float4 v1 = *(const float4*)&spf[s * 128 + ch + 4];
            float4* pf = (float4*)pooled;
            pf[g * 32 + (ch >> 2)] = v0;
            pf[g * 32 + (ch >> 2) + 1] = v1;
        }
    }
}

// ---- fused head: out = relu(pooled @ W1 + b1) @ W2 + b2, 8 graphs/block ----
__global__ __launch_bounds__(256) void k_head(const float* __restrict__ pooled,
                                              const float* __restrict__ W1v,
                                              const float* __restrict__ b1v,
                                              const float* __restrict__ W2v,
                                              const float* __restrict__ b2v,
                                              float* __restrict__ out) {
    __shared__ __align__(16) float sp[8 * 128];    // 4 KB
    __shared__ __align__(16) float smid[8 * 256];  // 8 KB
    __shared__ __align__(16) float sred[8 * 128];  // 4 KB
    int t = threadIdx.x;
    int base = blockIdx.x * 8;
    const float4* po4 = (const float4*)pooled;
    for (int i = t; i < 8 * 32; i += 256) ((float4*)sp)[i] = po4[base * 32 + i];
    __syncthreads();
    // phase 1: thread t owns lin1 output channel t (0..255)
    {
        float acc[8];
#pragma unroll
        for (int gl = 0; gl < 8; ++gl) acc[gl] = 0.f;
        const float4* sp4 = (const float4*)sp;
        for (int c4 = 0; c4 < 32; ++c4) {
            float w0 = W1v[(c4 * 4 + 0) * 256 + t];
            float w1 = W1v[(c4 * 4 + 1) * 256 + t];
            float w2 = W1v[(c4 * 4 + 2) * 256 + t];
            float w3 = W1v[(c4 * 4 + 3) * 256 + t];
#pragma unroll
            for (int gl = 0; gl < 8; ++gl) {
                float4 a = sp4[gl * 32 + c4];
                acc[gl] += a.x * w0 + a.y * w1 + a.z * w2 + a.w * w3;
            }
        }
        float bb = b1v[t];
#pragma unroll
        for (int gl = 0; gl < 8; ++gl) smid[gl * 256 + t] = fmaxf(acc[gl] + bb, 0.f);
    }
    __syncthreads();
    // phase 2: t = (half, k); each half sums its 128 c's; combine via LDS
    int k = t & 127, half = t >> 7;
    float acc2[8];
#pragma unroll
    for (int gl = 0; gl < 8; ++gl) acc2[gl] = 0.f;
    {
        const float* Wc = W2v + half * 128 * 128;    // rows half*128 .. +128
        const float4* sm4 = (const float4*)smid;
        for (int c4 = 0; c4 < 32; ++c4) {
            float w0 = Wc[(c4 * 4 + 0) * 128 + k];
            float w1 = Wc[(c4 * 4 + 1) * 128 + k];
            float w2 = Wc[(c4 * 4 + 2) * 128 + k];
            float w3 = Wc[(c4 * 4 + 3) * 128 + k];
#pragma unroll
            for (int gl = 0; gl < 8; ++gl) {
                float4 a = sm4[gl * 64 + half * 32 + c4];
                acc2[gl] += a.x * w0 + a.y * w1 + a.z * w2 + a.w * w3;
            }
        }
    }
    if (half == 1) {
#pragma unroll
        for (int gl = 0; gl < 8; ++gl) sred[gl * 128 + k] = acc2[gl];
    }
    __syncthreads();
    if (half == 0) {
        float bb = b2v[k];
#pragma unroll
        for (int gl = 0; gl < 8; ++gl)
            out[(base + gl) * 128 + k] = acc2[gl] + sred[gl * 128 + k] + bb;
    }
}

extern "C" void kernel_launch(void* const* d_in, const int* in_sizes, int n_in,
                              void* d_out, int out_size, void* d_ws, size_t ws_size,
                              hipStream_t stream) {
    (void)in_sizes; (void)n_in; (void)out_size; (void)ws_size;
    const float* x   = (const float*)d_in[0];
    const int* ei    = (const int*)d_in[1];
    const int* src = ei;
    const int* dst = ei + NE;
    const int* batch = (const int*)d_in[2];
    const float* nw  = (const float*)d_in[3];
    const float* nb  = (const float*)d_in[4];
    const float* W1  = (const float*)d_in[5];
    const float* b1  = (const float*)d_in[6];
    const float* W2  = (const float*)d_in[7];
    const float* b2  = (const float*)d_in[8];
    const float* W3  = (const float*)d_in[9];
    const float* b3  = (const float*)d_in[10];
    const float* l1W = (const float*)d_in[11];
    const float* l1b = (const float*)d_in[12];
    const float* l2W = (const float*)d_in[13];
    const float* l2b = (const float*)d_in[14];
    float* out = (float*)d_out;

    char* wsp = (char*)d_ws;
    int*   cnt      = (int*)wsp;   wsp += (size_t)NN * 4;        // becomes dis in place
    int*   rowstart = (int*)wsp;   wsp += (size_t)(NN + 1) * 4;
    int*   cursor   = (int*)wsp;   wsp += (size_t)NN * 4;
    int*   bsum     = (int*)wsp;   wsp += (size_t)NBS * 4;
    int*   bpre     = (int*)wsp;   wsp += (size_t)NBS * 4;
    int*   startg   = (int*)wsp;   wsp += (size_t)(NG + 1) * 4;
    int*   csr      = (int*)wsp;   wsp += (size_t)NE * 4;        // 3.2 MB
    wsp += ((256 - ((uintptr_t)wsp & 255)) & 255);
    unsigned short* w3hi = (unsigned short*)wsp; wsp += (size_t)128 * 64 * 2;  // 16 KB
    unsigned short* w3lo = (unsigned short*)wsp; wsp += (size_t)128 * 64 * 2;  // 16 KB
    float* scale   = (float*)wsp; wsp += (size_t)NG * 128 * 4;   // 4 MB
    float* shift   = (float*)wsp; wsp += (size_t)NG * 128 * 4;   // 4 MB
    float* pooled  = (float*)wsp; wsp += (size_t)NG * 128 * 4;   // 4 MB
    float* regionA = (float*)wsp; wsp += (size_t)NN * 64 * 4;    // p1|p2
    float* regionB = (float*)wsp; wsp += (size_t)NN * 64 * 4;    // p3h

    float* dis  = (float*)cnt;  // in-place after k_scanchunk
    float* p1   = regionA;
    float* p2   = regionA + (size_t)NN * 32;
    __hip_bfloat16* p3h = (__hip_bfloat16*)regionB;  // NN*64*2 B = 25.6 MB

    // CSR prep + starts + W3 split (independent work, one launch)
    hipMemsetAsync(cnt, 0, (size_t)NN * 4, stream);
    k_prep1<<<CNT_B + NBS + 32, 256, 0, stream>>>(dst, cnt, batch, startg, W3, w3hi, w3lo);
    k_blocksum<<<NBS, 256, 0, stream>>>(cnt, bsum);
    k_scanb<<<1, 1024, 0, stream>>>(bsum, bpre);
    k_scanchunk<<<NBS, 256, 0, stream>>>(cnt, bpre, rowstart, cursor);  // + dis, cursor

    // instance-norm stats (own kernel: clean HBM-bound pass)
    k_stats2<<<NG, 256, 0, stream>>>(x, startg, nw, nb, scale, shift);
    // conv1 + CSR fill fused (fill hides under conv1's compute)
    k_conv1f<<<2 * (NN / 64), 256, 0, stream>>>(x, batch, scale, shift, W1, dis, p1,
                                                src, dst, cursor, csr);
    k_gather1<<<NN * 8 / 256, 256, 0, stream>>>(p1, rowstart, csr, dis, b1, p2);
    // layer 2 (fused gather+matmul, bf16 p3 store)
    k_conv2g<<<NN / 16, 256, 0, stream>>>(p2, rowstart, csr, dis, W2, b2, p3h);
    // layer 3 (fused bf16 gather + MFMA matmul + low-atomic pool)
    hipMemsetAsync(pooled, 0, (size_t)NG * 128 * 4, stream);
    k_conv3mg<<<NN / 64, 256, 0, stream>>>(p3h, rowstart, csr, dis, w3hi, w3lo, b3, batch,
                                           (unsigned int*)pooled);

    // fused head (lin1 + lin2)
    k_head<<<NG / 8, 256, 0, stream>>>(pooled, l1W, l1b, l2W, l2b, out);
}

// Round 13
// 489.089 us; speedup vs baseline: 1.0123x; 1.0123x over previous
//
#include <hip/hip_runtime.h>
#include <hip/hip_bf16.h>
#include <stdint.h>

#define NN 200000
#define NE 800000
#define FIN 128
#define NG 8000
#define EPSV 1e-5f
#define NBS ((NN + 255) / 256)   // 782 scan blocks
#define CNT_B (NE / 256)         // 3125 (exact)

typedef __attribute__((ext_vector_type(8))) short bf16x8;   // 8 bf16 = 4 VGPRs
typedef __attribute__((ext_vector_type(4))) float f32x4;    // MFMA C/D

static __device__ __forceinline__ bf16x8 as_bf16x8(uint4 u) {
    union { uint4 u; bf16x8 v; } c; c.u = u; return c.v;
}

// bf16 helpers: load-convert (exact) and pack with RNE
static __device__ __forceinline__ void u2f(uint4 v, float4& lo, float4& hi) {
    lo.x = __uint_as_float(v.x << 16); lo.y = __uint_as_float(v.x & 0xffff0000u);
    lo.z = __uint_as_float(v.y << 16); lo.w = __uint_as_float(v.y & 0xffff0000u);
    hi.x = __uint_as_float(v.z << 16); hi.y = __uint_as_float(v.z & 0xffff0000u);
    hi.z = __uint_as_float(v.w << 16); hi.w = __uint_as_float(v.w & 0xffff0000u);
}
static __device__ __forceinline__ unsigned int pk(float a, float b) {
    __hip_bfloat16 x = __float2bfloat16(a), y = __float2bfloat16(b);
    return (unsigned int)(*(unsigned short*)&x) | ((unsigned int)(*(unsigned short*)&y) << 16);
}

// ---- prep1: [0,3125) edge-count histogram | [3125,3907) graph starts | [3907,3939) W3 split ----
__global__ __launch_bounds__(256) void k_prep1(const int* __restrict__ dst, int* __restrict__ cnt,
                                               const int* __restrict__ batch, int* __restrict__ startg,
                                               const float* __restrict__ W3,
                                               unsigned short* __restrict__ whi,
                                               unsigned short* __restrict__ wlo) {
    int b = blockIdx.x, t = threadIdx.x;
    if (b < CNT_B) {
        int e = b * 256 + t;
        atomicAdd(&cnt[dst[e]], 1);
    } else if (b < CNT_B + NBS) {
        int n = (b - CNT_B) * 256 + t;
        if (n >= NN) return;
        int bb = batch[n];
        int prev = (n == 0) ? -1 : batch[n - 1];
        for (int g = prev + 1; g <= bb; ++g) startg[g] = n;
        if (n == NN - 1) {
            for (int g = bb + 1; g <= NG; ++g) startg[g] = NN;
        }
    } else {
        int i = (b - CNT_B - NBS) * 256 + t;   // 8192 elems
        if (i >= 64 * 128) return;
        int n = i >> 6, k = i & 63;
        float w = W3[k * 128 + n];
        __hip_bfloat16 h = __float2bfloat16(w);
        float hf = __bfloat162float(h);
        __hip_bfloat16 l = __float2bfloat16(w - hf);
        whi[n * 64 + k] = *(unsigned short*)&h;
        wlo[n * 64 + k] = *(unsigned short*)&l;
    }
}

// ---- per-256-chunk sums ----
__global__ void k_blocksum(const int* __restrict__ cnt, int* __restrict__ bsum) {
    __shared__ int sh[256];
    int b = blockIdx.x, t = threadIdx.x;
    int idx = b * 256 + t;
    sh[t] = (idx < NN) ? cnt[idx] : 0;
    __syncthreads();
    for (int o = 128; o > 0; o >>= 1) {
        if (t < o) sh[t] += sh[t + o];
        __syncthreads();
    }
    if (t == 0) bsum[b] = sh[0];
}

// ---- single-block scan of chunk sums -> exclusive prefixes ----
__global__ __launch_bounds__(1024) void k_scanb(const int* __restrict__ bsum, int* __restrict__ bpre) {
    __shared__ int sh[1024];
    int t = threadIdx.x;
    int v = (t < NBS) ? bsum[t] : 0;
    sh[t] = v;
    __syncthreads();
    for (int o = 1; o < 1024; o <<= 1) {
        int add = (t >= o) ? sh[t - o] : 0;
        __syncthreads();
        sh[t] += add;
        __syncthreads();
    }
    if (t < NBS) bpre[t] = sh[t] - v;  // exclusive
}

// ---- per-chunk scan + offset -> rowstart/cursor; dis = rsqrt(1+deg) in place ----
__global__ void k_scanchunk(int* __restrict__ cnt, const int* __restrict__ bpre,
                            int* __restrict__ rowstart, int* __restrict__ cursor) {
    __shared__ int sh[256];
    int b = blockIdx.x, t = threadIdx.x;
    int idx = b * 256 + t;
    int v = (idx < NN) ? cnt[idx] : 0;
    sh[t] = v;
    __syncthreads();
    for (int o = 1; o < 256; o <<= 1) {
        int add = (t >= o) ? sh[t - o] : 0;
        __syncthreads();
        sh[t] += add;
        __syncthreads();
    }
    if (idx < NN) {
        int rs = bpre[b] + sh[t] - v;
        rowstart[idx] = rs;
        cursor[idx] = rs;
        ((float*)cnt)[idx] = rsqrtf(1.0f + (float)v);  // cnt -> dis in place
    }
    if (idx == 0) rowstart[NN] = NE;
}

// ---- fill CSR: csr[pos] = src, bucketed by dst (standalone: no LDS, max occupancy) ----
__global__ void k_fill(const int* __restrict__ src, const int* __restrict__ dst,
                       int* __restrict__ cursor, int* __restrict__ csr) {
    int e = blockIdx.x * 256 + threadIdx.x;
    if (e < NE) {
        int pos = atomicAdd(&cursor[dst[e]], 1);
        csr[pos] = src[e];
    }
}

// ---- per-graph instance-norm stats, latency-tolerant: 8 node slots x 32 float4 lanes ----
__global__ __launch_bounds__(256) void k_stats2(const float* __restrict__ x,
                                                const int* __restrict__ startg,
                                                const float* __restrict__ nw,
                                                const float* __restrict__ nb,
                                                float* __restrict__ scale,
                                                float* __restrict__ shift) {
    __shared__ float4 rsum[256], rsq[256];
    int g = blockIdx.x;
    int s = startg[g], e = startg[g + 1];
    if (s == e) return;
    int t = threadIdx.x;
    int slot = t >> 5, c4 = t & 31;
    const float4* x4 = (const float4*)x;
    float4 sum = {0.f, 0.f, 0.f, 0.f}, sq = {0.f, 0.f, 0.f, 0.f};
    for (int n = s + slot; n < e; n += 8) {
        float4 v = x4[n * 32 + c4];
        sum.x += v.x; sum.y += v.y; sum.z += v.z; sum.w += v.w;
        sq.x += v.x * v.x; sq.y += v.y * v.y; sq.z += v.z * v.z; sq.w += v.w * v.w;
    }
    rsum[slot * 32 + c4] = sum;
    rsq[slot * 32 + c4] = sq;
    __syncthreads();
    if (t < 32) {
        float4 S = rsum[t], Q = rsq[t];
#pragma unroll
        for (int sl = 1; sl < 8; ++sl) {
            float4 a = rsum[sl * 32 + t], bq = rsq[sl * 32 + t];
            S.x += a.x; S.y += a.y; S.z += a.z; S.w += a.w;
            Q.x += bq.x; Q.y += bq.y; Q.z += bq.z; Q.w += bq.w;
        }
        float inv = 1.0f / (float)(e - s);
        float w = nw[0], bb = nb[0];
        float4 sc, sh;
        {
            float m = S.x * inv, v = fmaxf(Q.x * inv - m * m, 0.f);
            float is = rsqrtf(v + EPSV); sc.x = is * w; sh.x = bb - m * is * w;
        }
        {
            float m = S.y * inv, v = fmaxf(Q.y * inv - m * m, 0.f);
            float is = rsqrtf(v + EPSV); sc.y = is * w; sh.y = bb - m * is * w;
        }
        {
            float m = S.z * inv, v = fmaxf(Q.z * inv - m * m, 0.f);
            float is = rsqrtf(v + EPSV); sc.z = is * w; sh.z = bb - m * is * w;
        }
        {
            float m = S.w * inv, v = fmaxf(Q.w * inv - m * m, 0.f);
            float is = rsqrtf(v + EPSV); sc.w = is * w; sh.w = bb - m * is * w;
        }
        ((float4*)scale)[g * 32 + t] = sc;
        ((float4*)shift)[g * 32 + t] = sh;
    }
}

// ---- conv1, lane-per-node: 64 nodes/block, lane=node, wave owns 8 output chans. ----
__global__ __launch_bounds__(256) void k_conv1s(const float* __restrict__ x,
                                                const int* __restrict__ batch,
                                                const float* __restrict__ scale,
                                                const float* __restrict__ shift,
                                                const float* __restrict__ W1,
                                                const float* __restrict__ dis,
                                                float* __restrict__ p1) {
    __shared__ float4 sx4[64 * 33];   // row stride 33 f4 (132 dwords = 4 mod 32: conflict-free)
    int t = threadIdx.x;
    int base = blockIdx.x * 64;       // NN % 64 == 0
    const float4* x4 = (const float4*)x;
    const float4* sc4 = (const float4*)scale;
    const float4* sh4 = (const float4*)shift;
    for (int i = t; i < 64 * 32; i += 256) {
        int nl = i >> 5, c4 = i & 31;
        int n = base + nl;
        int g = batch[n];
        float4 xv = x4[n * 32 + c4];
        float4 sc = sc4[g * 32 + c4];
        float4 sh = sh4[g * 32 + c4];
        float4 r;
        r.x = fmaf(xv.x, sc.x, sh.x);
        r.y = fmaf(xv.y, sc.y, sh.y);
        r.z = fmaf(xv.z, sc.z, sh.z);
        r.w = fmaf(xv.w, sc.w, sh.w);
        sx4[nl * 33 + c4] = r;
    }
    __syncthreads();
    int lane = t & 63;
    int kq = __builtin_amdgcn_readfirstlane(t >> 6) * 2;  // f4 column index (k0 = kq*4)
    const float4* W4 = (const float4*)W1;                 // [128 rows][8 f4]
    const float4* arow = &sx4[lane * 33];
    float4 acc0 = {0.f, 0.f, 0.f, 0.f}, acc1 = {0.f, 0.f, 0.f, 0.f};
#pragma unroll 4
    for (int c4 = 0; c4 < 32; ++c4) {
        float4 a = arow[c4];
        int rb = c4 * 32 + kq;        // rows 4*c4 .. 4*c4+3, cols kq,kq+1
        float4 wA0 = W4[rb +  0], wA1 = W4[rb +  1];
        float4 wB0 = W4[rb +  8], wB1 = W4[rb +  9];
        float4 wC0 = W4[rb + 16], wC1 = W4[rb + 17];
        float4 wD0 = W4[rb + 24], wD1 = W4[rb + 25];
        acc0.x += a.x * wA0.x + a.y * wB0.x + a.z * wC0.x + a.w * wD0.x;
        acc0.y += a.x * wA0.y + a.y * wB0.y + a.z * wC0.y + a.w * wD0.y;
        acc0.z += a.x * wA0.z + a.y * wB0.z + a.z * wC0.z + a.w * wD0.z;
        acc0.w += a.x * wA0.w + a.y * wB0.w + a.z * wC0.w + a.w * wD0.w;
        acc1.x += a.x * wA1.x + a.y * wB1.x + a.z * wC1.x + a.w * wD1.x;
        acc1.y += a.x * wA1.y + a.y * wB1.y + a.z * wC1.y + a.w * wD1.y;
        acc1.z += a.x * wA1.z + a.y * wB1.z + a.z * wC1.z + a.w * wD1.z;
        acc1.w += a.x * wA1.w + a.y * wB1.w + a.z * wC1.w + a.w * wD1.w;
    }
    int n = base + lane;
    float d = dis[n];
    float4 r0, r1;
    r0.x = acc0.x * d; r0.y = acc0.y * d; r0.z = acc0.z * d; r0.w = acc0.w * d;
    r1.x = acc1.x * d; r1.y = acc1.y * d; r1.z = acc1.z * d; r1.w = acc1.w * d;
    ((float4*)p1)[n * 8 + kq] = r0;
    ((float4*)p1)[n * 8 + kq + 1] = r1;
}

// ---- gather1 (C=32, float4) + conv1 epilogue: p2 = relu(dis*(self+neigh)+b1)*dis ----
__global__ __launch_bounds__(256) void k_gather1(const float* __restrict__ p1,
                                                 const int* __restrict__ rowstart,
                                                 const int* __restrict__ csr,
                                                 const float* __restrict__ dis,
                                                 const float* __restrict__ b1,
                                                 float* __restrict__ p2) {
    int tid = blockIdx.x * 256 + threadIdx.x;  // NN*8 threads
    int n = tid >> 3, c4 = tid & 7;
    const float4* p1_4 = (const float4*)p1;
    int s = rowstart[n], e = rowstart[n + 1];
    float4 agg = p1_4[n * 8 + c4];  // self-loop (p = h*dis already)
    int j = s;
    for (; j + 1 < e; j += 2) {
        float4 v0 = p1_4[csr[j] * 8 + c4];
        float4 v1 = p1_4[csr[j + 1] * 8 + c4];
        agg.x += v0.x + v1.x; agg.y += v0.y + v1.y;
        agg.z += v0.z + v1.z; agg.w += v0.w + v1.w;
    }
    if (j < e) {
        float4 v = p1_4[csr[j] * 8 + c4];
        agg.x += v.x; agg.y += v.y; agg.z += v.z; agg.w += v.w;
    }
    float d = dis[n];
    float4 bb = ((const float4*)b1)[c4];
    float4 r;
    r.x = fmaxf(d * agg.x + bb.x, 0.f) * d;
    r.y = fmaxf(d * agg.y + bb.y, 0.f) * d;
    r.z = fmaxf(d * agg.z + bb.z, 0.f) * d;
    r.w = fmaxf(d * agg.w + bb.w, 0.f) * d;
    ((float4*)p2)[n * 8 + c4] = r;
}

// ---- fused gather2 + conv2: p3(bf16) = relu((dis*(self+neigh))@W2 + b2)*dis  [32->64] ----
__global__ __launch_bounds__(256) void k_conv2g(const float* __restrict__ p2,
                                                const int* __restrict__ rowstart,
                                                const int* __restrict__ csr,
                                                const float* __restrict__ dis,
                                                const float* __restrict__ W2,
                                                const float* __restrict__ b2v,
                                                __hip_bfloat16* __restrict__ p3h) {
    __shared__ float sW[32 * 64];        // 8 KB
    __shared__ float4 spart[16 * 16];    // 4 KB
    __shared__ float sa[16 * 32];        // 2 KB
    int t = threadIdx.x;
    const float4* W4 = (const float4*)W2;
    for (int i = t; i < 32 * 64 / 4; i += 256) ((float4*)sW)[i] = W4[i];
    int base = blockIdx.x * 16;
    const float4* p2_4 = (const float4*)p2;
    {
        int node = t >> 4, c4 = t & 7, half = (t >> 3) & 1;
        int n = base + node;
        int s = rowstart[n], e = rowstart[n + 1];
        float4 agg = {0.f, 0.f, 0.f, 0.f};
        if (half == 0) {
            agg = p2_4[n * 8 + c4];  // self
            for (int j = s; j < e; j += 2) {
                float4 v = p2_4[csr[j] * 8 + c4];
                agg.x += v.x; agg.y += v.y; agg.z += v.z; agg.w += v.w;
            }
        } else {
            for (int j = s + 1; j < e; j += 2) {
                float4 v = p2_4[csr[j] * 8 + c4];
                agg.x += v.x; agg.y += v.y; agg.z += v.z; agg.w += v.w;
            }
        }
        spart[node * 16 + half * 8 + c4] = agg;
    }
    __syncthreads();
    if (t < 128) {
        int nd = t >> 3, cc = t & 7;
        float4 a = spart[nd * 16 + cc], b = spart[nd * 16 + 8 + cc];
        float d = dis[base + nd];
        float4 r;
        r.x = d * (a.x + b.x); r.y = d * (a.y + b.y);
        r.z = d * (a.z + b.z); r.w = d * (a.w + b.w);
        ((float4*)sa)[nd * 8 + cc] = r;
    }
    __syncthreads();
    int k = t & 63, grp = t >> 6;
    float acc[4] = {0.f, 0.f, 0.f, 0.f};
    for (int c = 0; c < 32; ++c) {
        float w = sW[c * 64 + k];
#pragma unroll
        for (int q = 0; q < 4; ++q) acc[q] += sa[(grp * 4 + q) * 32 + c] * w;
    }
    float bb = b2v[k];
#pragma unroll
    for (int q = 0; q < 4; ++q) {
        int n = base + grp * 4 + q;
        float h = fmaxf(acc[q] + bb, 0.f);
        p3h[n * 64 + k] = __float2bfloat16(h * dis[n]);
    }
}

// ---- conv3: fused edge-gather -> LDS -> MFMA -> low-atomic pool. ----
__global__ __launch_bounds__(256) void k_conv3mg(const __hip_bfloat16* __restrict__ p3h,
                                                 const int* __restrict__ rowstart,
                                                 const int* __restrict__ csr,
                                                 const float* __restrict__ dis,
                                                 const unsigned short* __restrict__ w3hi,
                                                 const unsigned short* __restrict__ w3lo,
                                                 const float* __restrict__ b3v,
                                                 const int* __restrict__ batch,
                                                 unsigned int* __restrict__ pooled) {
    __shared__ uint4 sa[64 * 9];     // 9.2 KB; dead after MFMA -> reused as spool (8 KB)
    __shared__ float sp[64 * 132];   // 33.8 KB, row stride 132 floats (pad)
    __shared__ int sbatch[64];
    int t = threadIdx.x;
    int base = blockIdx.x * 64;
    if (t < 64) sbatch[t] = batch[base + t];
    const uint4* p3q = (const uint4*)p3h;
    // fused gather3: 512 (node, c8) tasks, 2 per thread
    for (int i = t; i < 64 * 8; i += 256) {
        int nl = i >> 3, c8 = i & 7;
        int n = base + nl;
        int s = rowstart[n], e = rowstart[n + 1];
        float4 alo, ahi;
        u2f(p3q[n * 8 + c8], alo, ahi);  // self
        int j = s;
        for (; j + 1 < e; j += 2) {
            float4 l0, h0, l1, h1;
            u2f(p3q[csr[j] * 8 + c8], l0, h0);
            u2f(p3q[csr[j + 1] * 8 + c8], l1, h1);
            alo.x += l0.x + l1.x; alo.y += l0.y + l1.y;
            alo.z += l0.z + l1.z; alo.w += l0.w + l1.w;
            ahi.x += h0.x + h1.x; ahi.y += h0.y + h1.y;
            ahi.z += h0.z + h1.z; ahi.w += h0.w + h1.w;
        }
        if (j < e) {
            float4 l0, h0;
            u2f(p3q[csr[j] * 8 + c8], l0, h0);
            alo.x += l0.x; alo.y += l0.y; alo.z += l0.z; alo.w += l0.w;
            ahi.x += h0.x; ahi.y += h0.y; ahi.z += h0.z; ahi.w += h0.w;
        }
        float d = dis[n];
        uint4 o;
        o.x = pk(d * alo.x, d * alo.y);
        o.y = pk(d * alo.z, d * alo.w);
        o.z = pk(d * ahi.x, d * ahi.y);
        o.w = pk(d * ahi.z, d * ahi.w);
        sa[nl * 9 + c8] = o;
    }
    __syncthreads();
    int lane = t & 63, w = t >> 6;
    int h = lane >> 4;        // k-group 0..3 (k = kt*32 + h*8 + j)
    int cid = lane & 15;      // row (A) / col (B,C) within 16
    const uint4* WHq = (const uint4*)w3hi;   // [128 ch][8 granules]
    const uint4* WLq = (const uint4*)w3lo;
    uint4 bh[2][2], bl[2][2];
#pragma unroll
    for (int nl = 0; nl < 2; ++nl) {
        int n = (w * 2 + nl) * 16 + cid;
#pragma unroll
        for (int kt = 0; kt < 2; ++kt) {
            bh[nl][kt] = WHq[n * 8 + kt * 4 + h];
            bl[nl][kt] = WLq[n * 8 + kt * 4 + h];
        }
    }
    f32x4 acc[2][4];
#pragma unroll
    for (int nl = 0; nl < 2; ++nl)
#pragma unroll
        for (int mi = 0; mi < 4; ++mi) acc[nl][mi] = {0.f, 0.f, 0.f, 0.f};
#pragma unroll
    for (int mi = 0; mi < 4; ++mi) {
        int arow = (mi * 16 + cid) * 9;
        bf16x8 a0 = as_bf16x8(sa[arow + h]);        // kt=0
        bf16x8 a1 = as_bf16x8(sa[arow + 4 + h]);    // kt=1
#pragma unroll
        for (int nl = 0; nl < 2; ++nl) {
            acc[nl][mi] = __builtin_amdgcn_mfma_f32_16x16x32_bf16(a0, as_bf16x8(bh[nl][0]), acc[nl][mi], 0, 0, 0);
            acc[nl][mi] = __builtin_amdgcn_mfma_f32_16x16x32_bf16(a1, as_bf16x8(bh[nl][1]), acc[nl][mi], 0, 0, 0);
            acc[nl][mi] = __builtin_amdgcn_mfma_f32_16x16x32_bf16(a0, as_bf16x8(bl[nl][0]), acc[nl][mi], 0, 0, 0);
            acc[nl][mi] = __builtin_amdgcn_mfma_f32_16x16x32_bf16(a1, as_bf16x8(bl[nl][1]), acc[nl][mi], 0, 0, 0);
        }
    }
    // epilogue: bias + relu -> sp[node][ch]
#pragma unroll
    for (int nl = 0; nl < 2; ++nl) {
        int ch = (w * 2 + nl) * 16 + cid;
        float bb = b3v[ch];
#pragma unroll
        for (int mi = 0; mi < 4; ++mi) {
#pragma unroll
            for (int r = 0; r < 4; ++r) {
                int node_l = mi * 16 + h * 4 + r;
                sp[node_l * 132 + ch] = fmaxf(acc[nl][mi][r] + bb, 0.f);
            }
        }
    }
    __syncthreads();
    // Phase C: init interior-graph pool (reuse sa: 16 slots x 128 ch of uint)
    unsigned int* spool = (unsigned int*)sa;
    for (int i = t; i < 16 * 128; i += 256) spool[i] = 0u;
    __syncthreads();
    int g0 = sbatch[0], g63 = sbatch[63];
    // Phase D: run-length pool; interior -> LDS atomic, boundary/overflow -> global
    int k4 = t & 31, n0 = (t >> 5) * 8;
    int curg = sbatch[n0];
    float4 cm = {0.f, 0.f, 0.f, 0.f};
#pragma unroll
    for (int ii = 0; ii < 8; ++ii) {
        int g = sbatch[n0 + ii];
        float4 hv = *(const float4*)&sp[(n0 + ii) * 132 + k4 * 4];
        if (g != curg) {
            int s = curg - g0 - 1;
            if (s >= 0 && curg < g63 && s < 16) {
                unsigned int* d = spool + s * 128 + k4 * 4;
                atomicMax(d + 0, __float_as_uint(cm.x));
                atomicMax(d + 1, __float_as_uint(cm.y));
                atomicMax(d + 2, __float_as_uint(cm.z));
                atomicMax(d + 3, __float_as_uint(cm.w));
            } else {
                unsigned int* d = pooled + curg * 128 + k4 * 4;
                atomicMax(d + 0, __float_as_uint(cm.x));
                atomicMax(d + 1, __float_as_uint(cm.y));
                atomicMax(d + 2, __float_as_uint(cm.z));
                atomicMax(d + 3, __float_as_uint(cm.w));
            }
            cm = {0.f, 0.f, 0.f, 0.f};
            curg = g;
        }
        cm.x = fmaxf(cm.x, hv.x);
        cm.y = fmaxf(cm.y, hv.y);
        cm.z = fmaxf(cm.z, hv.z);
        cm.w = fmaxf(cm.w, hv.w);
    }
    {
        int s = curg - g0 - 1;
        if (s >= 0 && curg < g63 && s < 16) {
            unsigned int* d = spool + s * 128 + k4 * 4;
            atomicMax(d + 0, __float_as_uint(cm.x));
            atomicMax(d + 1, __float_as_uint(cm.y));
            atomicMax(d + 2, __float_as_uint(cm.z));
            atomicMax(d + 3, __float_as_uint(cm.w));
        } else {
            unsigned int* d = pooled + curg * 128 + k4 * 4;
            atomicMax(d + 0, __float_as_uint(cm.x));
            atomicMax(d + 1, __float_as_uint(cm.y));
            atomicMax(d + 2, __float_as_uint(cm.z));
            atomicMax(d + 3, __float_as_uint(cm.w));
        }
    }
    __syncthreads();
    // Phase E: interior graphs have this block as sole writer -> plain float4 stores
    {
        int s = t >> 4;              // slot 0..15
        int g = g0 + 1 + s;
        if (g < g63) {
            int ch = (t & 15) * 8;
            const float* spf = (const float*)spool;
            float4 v0 = *(const float4*)&spf[s * 128 + ch];
            float4 v1 = *(const float4*)&spf[s * 128 + ch + 4];
            float4* pf = (float4*)pooled;
            pf[g * 32 + (ch >> 2)] = v0;
            pf[g * 32 + (ch >> 2) + 1] = v1;
        }
    }
}

// ---- fused head: out = relu(pooled @ W1 + b1) @ W2 + b2, 8 graphs/block ----
__global__ __launch_bounds__(256) void k_head(const float* __restrict__ pooled,
                                              const float* __restrict__ W1v,
                                              const float* __restrict__ b1v,
                                              const float* __restrict__ W2v,
                                              const float* __restrict__ b2v,
                                              float* __restrict__ out) {
    __shared__ __align__(16) float sp[8 * 128];    // 4 KB
    __shared__ __align__(16) float smid[8 * 256];  // 8 KB
    __shared__ __align__(16) float sred[8 * 128];  // 4 KB
    int t = threadIdx.x;
    int base = blockIdx.x * 8;
    const float4* po4 = (const float4*)pooled;
    for (int i = t; i < 8 * 32; i += 256) ((float4*)sp)[i] = po4[base * 32 + i];
    __syncthreads();
    // phase 1: thread t owns lin1 output channel t (0..255)
    {
        float acc[8];
#pragma unroll
        for (int gl = 0; gl < 8; ++gl) acc[gl] = 0.f;
        const float4* sp4 = (const float4*)sp;
        for (int c4 = 0; c4 < 32; ++c4) {
            float w0 = W1v[(c4 * 4 + 0) * 256 + t];
            float w1 = W1v[(c4 * 4 + 1) * 256 + t];
            float w2 = W1v[(c4 * 4 + 2) * 256 + t];
            float w3 = W1v[(c4 * 4 + 3) * 256 + t];
#pragma unroll
            for (int gl = 0; gl < 8; ++gl) {
                float4 a = sp4[gl * 32 + c4];
                acc[gl] += a.x * w0 + a.y * w1 + a.z * w2 + a.w * w3;
            }
        }
        float bb = b1v[t];
#pragma unroll
        for (int gl = 0; gl < 8; ++gl) smid[gl * 256 + t] = fmaxf(acc[gl] + bb, 0.f);
    }
    __syncthreads();
    // phase 2: t = (half, k); each half sums its 128 c's; combine via LDS
    int k = t & 127, half = t >> 7;
    float acc2[8];
#pragma unroll
    for (int gl = 0; gl < 8; ++gl) acc2[gl] = 0.f;
    {
        const float* Wc = W2v + half * 128 * 128;    // rows half*128 .. +128
        const float4* sm4 = (const float4*)smid;
        for (int c4 = 0; c4 < 32; ++c4) {
            float w0 = Wc[(c4 * 4 + 0) * 128 + k];
            float w1 = Wc[(c4 * 4 + 1) * 128 + k];
            float w2 = Wc[(c4 * 4 + 2) * 128 + k];
            float w3 = Wc[(c4 * 4 + 3) * 128 + k];
#pragma unroll
            for (int gl = 0; gl < 8; ++gl) {
                float4 a = sm4[gl * 64 + half * 32 + c4];
                acc2[gl] += a.x * w0 + a.y * w1 + a.z * w2 + a.w * w3;
            }
        }
    }
    if (half == 1) {
#pragma unroll
        for (int gl = 0; gl < 8; ++gl) sred[gl * 128 + k] = acc2[gl];
    }
    __syncthreads();
    if (half == 0) {
        float bb = b2v[k];
#pragma unroll
        for (int gl = 0; gl < 8; ++gl)
            out[(base + gl) * 128 + k] = acc2[gl] + sred[gl * 128 + k] + bb;
    }
}

extern "C" void kernel_launch(void* const* d_in, const int* in_sizes, int n_in,
                              void* d_out, int out_size, void* d_ws, size_t ws_size,
                              hipStream_t stream) {
    (void)in_sizes; (void)n_in; (void)out_size; (void)ws_size;
    const float* x   = (const float*)d_in[0];
    const int* ei    = (const int*)d_in[1];
    const int* src = ei;
    const int* dst = ei + NE;
    const int* batch = (const int*)d_in[2];
    const float* nw  = (const float*)d_in[3];
    const float* nb  = (const float*)d_in[4];
    const float* W1  = (const float*)d_in[5];
    const float* b1  = (const float*)d_in[6];
    const float* W2  = (const float*)d_in[7];
    const float* b2  = (const float*)d_in[8];
    const float* W3  = (const float*)d_in[9];
    const float* b3  = (const float*)d_in[10];
    const float* l1W = (const float*)d_in[11];
    const float* l1b = (const float*)d_in[12];
    const float* l2W = (const float*)d_in[13];
    const float* l2b = (const float*)d_in[14];
    float* out = (float*)d_out;

    char* wsp = (char*)d_ws;
    int*   cnt      = (int*)wsp;   wsp += (size_t)NN * 4;        // becomes dis in place
    int*   rowstart = (int*)wsp;   wsp += (size_t)(NN + 1) * 4;
    int*   cursor   = (int*)wsp;   wsp += (size_t)NN * 4;
    int*   bsum     = (int*)wsp;   wsp += (size_t)NBS * 4;
    int*   bpre     = (int*)wsp;   wsp += (size_t)NBS * 4;
    int*   startg   = (int*)wsp;   wsp += (size_t)(NG + 1) * 4;
    int*   csr      = (int*)wsp;   wsp += (size_t)NE * 4;        // 3.2 MB
    wsp += ((256 - ((uintptr_t)wsp & 255)) & 255);
    unsigned short* w3hi = (unsigned short*)wsp; wsp += (size_t)128 * 64 * 2;  // 16 KB
    unsigned short* w3lo = (unsigned short*)wsp; wsp += (size_t)128 * 64 * 2;  // 16 KB
    float* scale   = (float*)wsp; wsp += (size_t)NG * 128 * 4;   // 4 MB
    float* shift   = (float*)wsp; wsp += (size_t)NG * 128 * 4;   // 4 MB
    float* pooled  = (float*)wsp; wsp += (size_t)NG * 128 * 4;   // 4 MB
    float* regionA = (float*)wsp; wsp += (size_t)NN * 64 * 4;    // p1|p2
    float* regionB = (float*)wsp; wsp += (size_t)NN * 64 * 4;    // p3h

    float* dis  = (float*)cnt;  // in-place after k_scanchunk
    float* p1   = regionA;
    float* p2   = regionA + (size_t)NN * 32;
    __hip_bfloat16* p3h = (__hip_bfloat16*)regionB;  // NN*64*2 B = 25.6 MB

    // CSR prep + starts + W3 split (independent work, one launch)
    hipMemsetAsync(cnt, 0, (size_t)NN * 4, stream);
    k_prep1<<<CNT_B + NBS + 32, 256, 0, stream>>>(dst, cnt, batch, startg, W3, w3hi, w3lo);
    k_blocksum<<<NBS, 256, 0, stream>>>(cnt, bsum);
    k_scanb<<<1, 1024, 0, stream>>>(bsum, bpre);
    k_scanchunk<<<NBS, 256, 0, stream>>>(cnt, bpre, rowstart, cursor);  // + dis, cursor
    // CSR fill standalone (no LDS -> full occupancy for the latency-bound scatter)
    k_fill<<<(NE + 255) / 256, 256, 0, stream>>>(src, dst, cursor, csr);

    // instance-norm stats (own kernel: clean HBM-bound pass)
    k_stats2<<<NG, 256, 0, stream>>>(x, startg, nw, nb, scale, shift);
    // layer 1
    k_conv1s<<<NN / 64, 256, 0, stream>>>(x, batch, scale, shift, W1, dis, p1);
    k_gather1<<<NN * 8 / 256, 256, 0, stream>>>(p1, rowstart, csr, dis, b1, p2);
    // layer 2 (fused gather+matmul, bf16 p3 store)
    k_conv2g<<<NN / 16, 256, 0, stream>>>(p2, rowstart, csr, dis, W2, b2, p3h);
    // layer 3 (fused bf16 gather + MFMA matmul + low-atomic pool)
    hipMemsetAsync(pooled, 0, (size_t)NG * 128 * 4, stream);
    k_conv3mg<<<NN / 64, 256, 0, stream>>>(p3h, rowstart, csr, dis, w3hi, w3lo, b3, batch,
                                           (unsigned int*)pooled);

    // fused head (lin1 + lin2)
    k_head<<<NG / 8, 256, 0, stream>>>(pooled, l1W, l1b, l2W, l2b, out);
}

// Round 15
// 474.888 us; speedup vs baseline: 1.0426x; 1.0299x over previous
//
#include <hip/hip_runtime.h>
#include <hip/hip_bf16.h>
#include <stdint.h>

#define NN 200000
#define NE 800000
#define FIN 128
#define NG 8000
#define EPSV 1e-5f
#define NBS ((NN + 255) / 256)   // 782 scan blocks
#define CNT_B (NE / 256)         // 3125 (exact)

typedef __attribute__((ext_vector_type(8))) short bf16x8;   // 8 bf16 = 4 VGPRs
typedef __attribute__((ext_vector_type(4))) float f32x4;    // MFMA C/D

static __device__ __forceinline__ bf16x8 as_bf16x8(uint4 u) {
    union { uint4 u; bf16x8 v; } c; c.u = u; return c.v;
}

// bf16 helpers: load-convert (exact) and pack with RNE
static __device__ __forceinline__ void u2f(uint4 v, float4& lo, float4& hi) {
    lo.x = __uint_as_float(v.x << 16); lo.y = __uint_as_float(v.x & 0xffff0000u);
    lo.z = __uint_as_float(v.y << 16); lo.w = __uint_as_float(v.y & 0xffff0000u);
    hi.x = __uint_as_float(v.z << 16); hi.y = __uint_as_float(v.z & 0xffff0000u);
    hi.z = __uint_as_float(v.w << 16); hi.w = __uint_as_float(v.w & 0xffff0000u);
}
static __device__ __forceinline__ unsigned int pk(float a, float b) {
    __hip_bfloat16 x = __float2bfloat16(a), y = __float2bfloat16(b);
    return (unsigned int)(*(unsigned short*)&x) | ((unsigned int)(*(unsigned short*)&y) << 16);
}

// ---- prep1: [0,3125) edge-count histogram | [3125,3907) graph starts | [3907,3939) W3 split ----
__global__ __launch_bounds__(256) void k_prep1(const int* __restrict__ dst, int* __restrict__ cnt,
                                               const int* __restrict__ batch, int* __restrict__ startg,
                                               const float* __restrict__ W3,
                                               unsigned short* __restrict__ whi,
                                               unsigned short* __restrict__ wlo) {
    int b = blockIdx.x, t = threadIdx.x;
    if (b < CNT_B) {
        int e = b * 256 + t;
        atomicAdd(&cnt[dst[e]], 1);
    } else if (b < CNT_B + NBS) {
        int n = (b - CNT_B) * 256 + t;
        if (n >= NN) return;
        int bb = batch[n];
        int prev = (n == 0) ? -1 : batch[n - 1];
        for (int g = prev + 1; g <= bb; ++g) startg[g] = n;
        if (n == NN - 1) {
            for (int g = bb + 1; g <= NG; ++g) startg[g] = NN;
        }
    } else {
        int i = (b - CNT_B - NBS) * 256 + t;   // 8192 elems
        if (i >= 64 * 128) return;
        int n = i >> 6, k = i & 63;
        float w = W3[k * 128 + n];
        __hip_bfloat16 h = __float2bfloat16(w);
        float hf = __bfloat162float(h);
        __hip_bfloat16 l = __float2bfloat16(w - hf);
        whi[n * 64 + k] = *(unsigned short*)&h;
        wlo[n * 64 + k] = *(unsigned short*)&l;
    }
}

// ---- per-256-chunk sums ----
__global__ void k_blocksum(const int* __restrict__ cnt, int* __restrict__ bsum) {
    __shared__ int sh[256];
    int b = blockIdx.x, t = threadIdx.x;
    int idx = b * 256 + t;
    sh[t] = (idx < NN) ? cnt[idx] : 0;
    __syncthreads();
    for (int o = 128; o > 0; o >>= 1) {
        if (t < o) sh[t] += sh[t + o];
        __syncthreads();
    }
    if (t == 0) bsum[b] = sh[0];
}

// ---- single-block scan of chunk sums -> exclusive prefixes ----
__global__ __launch_bounds__(1024) void k_scanb(const int* __restrict__ bsum, int* __restrict__ bpre) {
    __shared__ int sh[1024];
    int t = threadIdx.x;
    int v = (t < NBS) ? bsum[t] : 0;
    sh[t] = v;
    __syncthreads();
    for (int o = 1; o < 1024; o <<= 1) {
        int add = (t >= o) ? sh[t - o] : 0;
        __syncthreads();
        sh[t] += add;
        __syncthreads();
    }
    if (t < NBS) bpre[t] = sh[t] - v;  // exclusive
}

// ---- per-chunk scan + offset -> rowstart/cursor; dis = rsqrt(1+deg) in place ----
__global__ void k_scanchunk(int* __restrict__ cnt, const int* __restrict__ bpre,
                            int* __restrict__ rowstart, int* __restrict__ cursor) {
    __shared__ int sh[256];
    int b = blockIdx.x, t = threadIdx.x;
    int idx = b * 256 + t;
    int v = (idx < NN) ? cnt[idx] : 0;
    sh[t] = v;
    __syncthreads();
    for (int o = 1; o < 256; o <<= 1) {
        int add = (t >= o) ? sh[t - o] : 0;
        __syncthreads();
        sh[t] += add;
        __syncthreads();
    }
    if (idx < NN) {
        int rs = bpre[b] + sh[t] - v;
        rowstart[idx] = rs;
        cursor[idx] = rs;
        ((float*)cnt)[idx] = rsqrtf(1.0f + (float)v);  // cnt -> dis in place
    }
    if (idx == 0) rowstart[NN] = NE;
}

// ---- fill CSR: csr[pos] = src, bucketed by dst (standalone: no LDS, max occupancy) ----
__global__ void k_fill(const int* __restrict__ src, const int* __restrict__ dst,
                       int* __restrict__ cursor, int* __restrict__ csr) {
    int e = blockIdx.x * 256 + threadIdx.x;
    if (e < NE) {
        int pos = atomicAdd(&cursor[dst[e]], 1);
        csr[pos] = src[e];
    }
}

// ---- per-graph instance-norm stats, latency-tolerant: 8 node slots x 32 float4 lanes ----
__global__ __launch_bounds__(256) void k_stats2(const float* __restrict__ x,
                                                const int* __restrict__ startg,
                                                const float* __restrict__ nw,
                                                const float* __restrict__ nb,
                                                float* __restrict__ scale,
                                                float* __restrict__ shift) {
    __shared__ float4 rsum[256], rsq[256];
    int g = blockIdx.x;
    int s = startg[g], e = startg[g + 1];
    if (s == e) return;
    int t = threadIdx.x;
    int slot = t >> 5, c4 = t & 31;
    const float4* x4 = (const float4*)x;
    float4 sum = {0.f, 0.f, 0.f, 0.f}, sq = {0.f, 0.f, 0.f, 0.f};
    for (int n = s + slot; n < e; n += 8) {
        float4 v = x4[n * 32 + c4];
        sum.x += v.x; sum.y += v.y; sum.z += v.z; sum.w += v.w;
        sq.x += v.x * v.x; sq.y += v.y * v.y; sq.z += v.z * v.z; sq.w += v.w * v.w;
    }
    rsum[slot * 32 + c4] = sum;
    rsq[slot * 32 + c4] = sq;
    __syncthreads();
    if (t < 32) {
        float4 S = rsum[t], Q = rsq[t];
#pragma unroll
        for (int sl = 1; sl < 8; ++sl) {
            float4 a = rsum[sl * 32 + t], bq = rsq[sl * 32 + t];
            S.x += a.x; S.y += a.y; S.z += a.z; S.w += a.w;
            Q.x += bq.x; Q.y += bq.y; Q.z += bq.z; Q.w += bq.w;
        }
        float inv = 1.0f / (float)(e - s);
        float w = nw[0], bb = nb[0];
        float4 sc, sh;
        {
            float m = S.x * inv, v = fmaxf(Q.x * inv - m * m, 0.f);
            float is = rsqrtf(v + EPSV); sc.x = is * w; sh.x = bb - m * is * w;
        }
        {
            float m = S.y * inv, v = fmaxf(Q.y * inv - m * m, 0.f);
            float is = rsqrtf(v + EPSV); sc.y = is * w; sh.y = bb - m * is * w;
        }
        {
            float m = S.z * inv, v = fmaxf(Q.z * inv - m * m, 0.f);
            float is = rsqrtf(v + EPSV); sc.z = is * w; sh.z = bb - m * is * w;
        }
        {
            float m = S.w * inv, v = fmaxf(Q.w * inv - m * m, 0.f);
            float is = rsqrtf(v + EPSV); sc.w = is * w; sh.w = bb - m * is * w;
        }
        ((float4*)scale)[g * 32 + t] = sc;
        ((float4*)shift)[g * 32 + t] = sh;
    }
}

// ---- conv1, lane-per-node: 64 nodes/block, lane=node, wave owns 8 output chans. ----
__global__ __launch_bounds__(256) void k_conv1s(const float* __restrict__ x,
                                                const int* __restrict__ batch,
                                                const float* __restrict__ scale,
                                                const float* __restrict__ shift,
                                                const float* __restrict__ W1,
                                                const float* __restrict__ dis,
                                                float* __restrict__ p1) {
    __shared__ float4 sx4[64 * 33];   // row stride 33 f4 (132 dwords = 4 mod 32: conflict-free)
    int t = threadIdx.x;
    int base = blockIdx.x * 64;       // NN % 64 == 0
    const float4* x4 = (const float4*)x;
    const float4* sc4 = (const float4*)scale;
    const float4* sh4 = (const float4*)shift;
    for (int i = t; i < 64 * 32; i += 256) {
        int nl = i >> 5, c4 = i & 31;
        int n = base + nl;
        int g = batch[n];
        float4 xv = x4[n * 32 + c4];
        float4 sc = sc4[g * 32 + c4];
        float4 sh = sh4[g * 32 + c4];
        float4 r;
        r.x = fmaf(xv.x, sc.x, sh.x);
        r.y = fmaf(xv.y, sc.y, sh.y);
        r.z = fmaf(xv.z, sc.z, sh.z);
        r.w = fmaf(xv.w, sc.w, sh.w);
        sx4[nl * 33 + c4] = r;
    }
    __syncthreads();
    int lane = t & 63;
    int kq = __builtin_amdgcn_readfirstlane(t >> 6) * 2;  // f4 column index (k0 = kq*4)
    const float4* W4 = (const float4*)W1;                 // [128 rows][8 f4]
    const float4* arow = &sx4[lane * 33];
    float4 acc0 = {0.f, 0.f, 0.f, 0.f}, acc1 = {0.f, 0.f, 0.f, 0.f};
#pragma unroll 4
    for (int c4 = 0; c4 < 32; ++c4) {
        float4 a = arow[c4];
        int rb = c4 * 32 + kq;        // rows 4*c4 .. 4*c4+3, cols kq,kq+1
        float4 wA0 = W4[rb +  0], wA1 = W4[rb +  1];
        float4 wB0 = W4[rb +  8], wB1 = W4[rb +  9];
        float4 wC0 = W4[rb + 16], wC1 = W4[rb + 17];
        float4 wD0 = W4[rb + 24], wD1 = W4[rb + 25];
        acc0.x += a.x * wA0.x + a.y * wB0.x + a.z * wC0.x + a.w * wD0.x;
        acc0.y += a.x * wA0.y + a.y * wB0.y + a.z * wC0.y + a.w * wD0.y;
        acc0.z += a.x * wA0.z + a.y * wB0.z + a.z * wC0.z + a.w * wD0.z;
        acc0.w += a.x * wA0.w + a.y * wB0.w + a.z * wC0.w + a.w * wD0.w;
        acc1.x += a.x * wA1.x + a.y * wB1.x + a.z * wC1.x + a.w * wD1.x;
        acc1.y += a.x * wA1.y + a.y * wB1.y + a.z * wC1.y + a.w * wD1.y;
        acc1.z += a.x * wA1.z + a.y * wB1.z + a.z * wC1.z + a.w * wD1.z;
        acc1.w += a.x * wA1.w + a.y * wB1.w + a.z * wC1.w + a.w * wD1.w;
    }
    int n = base + lane;
    float d = dis[n];
    float4 r0, r1;
    r0.x = acc0.x * d; r0.y = acc0.y * d; r0.z = acc0.z * d; r0.w = acc0.w * d;
    r1.x = acc1.x * d; r1.y = acc1.y * d; r1.z = acc1.z * d; r1.w = acc1.w * d;
    ((float4*)p1)[n * 8 + kq] = r0;
    ((float4*)p1)[n * 8 + kq + 1] = r1;
}

// ---- gather1 (C=32, float4) + conv1 epilogue: p2 = relu(dis*(self+neigh)+b1)*dis ----
__global__ __launch_bounds__(256) void k_gather1(const float* __restrict__ p1,
                                                 const int* __restrict__ rowstart,
                                                 const int* __restrict__ csr,
                                                 const float* __restrict__ dis,
                                                 const float* __restrict__ b1,
                                                 float* __restrict__ p2) {
    int tid = blockIdx.x * 256 + threadIdx.x;  // NN*8 threads
    int n = tid >> 3, c4 = tid & 7;
    const float4* p1_4 = (const float4*)p1;
    int s = rowstart[n], e = rowstart[n + 1];
    float4 agg = p1_4[n * 8 + c4];  // self-loop (p = h*dis already)
    int j = s;
    for (; j + 1 < e; j += 2) {
        float4 v0 = p1_4[csr[j] * 8 + c4];
        float4 v1 = p1_4[csr[j + 1] * 8 + c4];
        agg.x += v0.x + v1.x; agg.y += v0.y + v1.y;
        agg.z += v0.z + v1.z; agg.w += v0.w + v1.w;
    }
    if (j < e) {
        float4 v = p1_4[csr[j] * 8 + c4];
        agg.x += v.x; agg.y += v.y; agg.z += v.z; agg.w += v.w;
    }
    float d = dis[n];
    float4 bb = ((const float4*)b1)[c4];
    float4 r;
    r.x = fmaxf(d * agg.x + bb.x, 0.f) * d;
    r.y = fmaxf(d * agg.y + bb.y, 0.f) * d;
    r.z = fmaxf(d * agg.z + bb.z, 0.f) * d;
    r.w = fmaxf(d * agg.w + bb.w, 0.f) * d;
    ((float4*)p2)[n * 8 + c4] = r;
}

// ---- fused gather2 + conv2: p3(bf16) = relu((dis*(self+neigh))@W2 + b2)*dis  [32->64] ----
__global__ __launch_bounds__(256) void k_conv2g(const float* __restrict__ p2,
                                                const int* __restrict__ rowstart,
                                                const int* __restrict__ csr,
                                                const float* __restrict__ dis,
                                                const float* __restrict__ W2,
                                                const float* __restrict__ b2v,
                                                __hip_bfloat16* __restrict__ p3h) {
    __shared__ float sW[32 * 64];        // 8 KB
    __shared__ float4 spart[16 * 16];    // 4 KB
    __shared__ float sa[16 * 32];        // 2 KB
    int t = threadIdx.x;
    const float4* W4 = (const float4*)W2;
    for (int i = t; i < 32 * 64 / 4; i += 256) ((float4*)sW)[i] = W4[i];
    int base = blockIdx.x * 16;
    const float4* p2_4 = (const float4*)p2;
    {
        int node = t >> 4, c4 = t & 7, half = (t >> 3) & 1;
        int n = base + node;
        int s = rowstart[n], e = rowstart[n + 1];
        float4 agg = {0.f, 0.f, 0.f, 0.f};
        if (half == 0) {
            agg = p2_4[n * 8 + c4];  // self
            for (int j = s; j < e; j += 2) {
                float4 v = p2_4[csr[j] * 8 + c4];
                agg.x += v.x; agg.y += v.y; agg.z += v.z; agg.w += v.w;
            }
        } else {
            for (int j = s + 1; j < e; j += 2) {
                float4 v = p2_4[csr[j] * 8 + c4];
                agg.x += v.x; agg.y += v.y; agg.z += v.z; agg.w += v.w;
            }
        }
        spart[node * 16 + half * 8 + c4] = agg;
    }
    __syncthreads();
    if (t < 128) {
        int nd = t >> 3, cc = t & 7;
        float4 a = spart[nd * 16 + cc], b = spart[nd * 16 + 8 + cc];
        float d = dis[base + nd];
        float4 r;
        r.x = d * (a.x + b.x); r.y = d * (a.y + b.y);
        r.z = d * (a.z + b.z); r.w = d * (a.w + b.w);
        ((float4*)sa)[nd * 8 + cc] = r;
    }
    __syncthreads();
    int k = t & 63, grp = t >> 6;
    float acc[4] = {0.f, 0.f, 0.f, 0.f};
    for (int c = 0; c < 32; ++c) {
        float w = sW[c * 64 + k];
#pragma unroll
        for (int q = 0; q < 4; ++q) acc[q] += sa[(grp * 4 + q) * 32 + c] * w;
    }
    float bb = b2v[k];
#pragma unroll
    for (int q = 0; q < 4; ++q) {
        int n = base + grp * 4 + q;
        float h = fmaxf(acc[q] + bb, 0.f);
        p3h[n * 64 + k] = __float2bfloat16(h * dis[n]);
    }
}

// ---- conv3: fused edge-gather -> LDS -> MFMA -> register run-length pool.
//      No sp transpose buffer: each lane's acc covers 16 ascending nodes x 2 chans,
//      pooled directly from registers (max is assoc/comm -> bit-identical).
//      LDS 43.5 -> 9.5 KB: occupancy 3 -> ~6 blocks/CU for the latency-bound gather. ----
__global__ __launch_bounds__(256) void k_conv3mg(const __hip_bfloat16* __restrict__ p3h,
                                                 const int* __restrict__ rowstart,
                                                 const int* __restrict__ csr,
                                                 const float* __restrict__ dis,
                                                 const unsigned short* __restrict__ w3hi,
                                                 const unsigned short* __restrict__ w3lo,
                                                 const float* __restrict__ b3v,
                                                 const int* __restrict__ batch,
                                                 unsigned int* __restrict__ pooled) {
    __shared__ uint4 sa[64 * 9];     // 9.2 KB; reused as spool (8 KB) after MFMA
    __shared__ int sbatch[64];
    int t = threadIdx.x;
    int base = blockIdx.x * 64;
    if (t < 64) sbatch[t] = batch[base + t];
    const uint4* p3q = (const uint4*)p3h;
    // fused gather3: 512 (node, c8) tasks, 2 per thread
    for (int i = t; i < 64 * 8; i += 256) {
        int nl = i >> 3, c8 = i & 7;
        int n = base + nl;
        int s = rowstart[n], e = rowstart[n + 1];
        float4 alo, ahi;
        u2f(p3q[n * 8 + c8], alo, ahi);  // self
        int j = s;
        for (; j + 1 < e; j += 2) {
            float4 l0, h0, l1, h1;
            u2f(p3q[csr[j] * 8 + c8], l0, h0);
            u2f(p3q[csr[j + 1] * 8 + c8], l1, h1);
            alo.x += l0.x + l1.x; alo.y += l0.y + l1.y;
            alo.z += l0.z + l1.z; alo.w += l0.w + l1.w;
            ahi.x += h0.x + h1.x; ahi.y += h0.y + h1.y;
            ahi.z += h0.z + h1.z; ahi.w += h0.w + h1.w;
        }
        if (j < e) {
            float4 l0, h0;
            u2f(p3q[csr[j] * 8 + c8], l0, h0);
            alo.x += l0.x; alo.y += l0.y; alo.z += l0.z; alo.w += l0.w;
            ahi.x += h0.x; ahi.y += h0.y; ahi.z += h0.z; ahi.w += h0.w;
        }
        float d = dis[n];
        uint4 o;
        o.x = pk(d * alo.x, d * alo.y);
        o.y = pk(d * alo.z, d * alo.w);
        o.z = pk(d * ahi.x, d * ahi.y);
        o.w = pk(d * ahi.z, d * ahi.w);
        sa[nl * 9 + c8] = o;
    }
    __syncthreads();
    int lane = t & 63, w = t >> 6;
    int h = lane >> 4;        // k-group 0..3 (k = kt*32 + h*8 + j)
    int cid = lane & 15;      // row (A) / col (B,C) within 16
    const uint4* WHq = (const uint4*)w3hi;   // [128 ch][8 granules]
    const uint4* WLq = (const uint4*)w3lo;
    uint4 bh[2][2], bl[2][2];
#pragma unroll
    for (int nl = 0; nl < 2; ++nl) {
        int n = (w * 2 + nl) * 16 + cid;
#pragma unroll
        for (int kt = 0; kt < 2; ++kt) {
            bh[nl][kt] = WHq[n * 8 + kt * 4 + h];
            bl[nl][kt] = WLq[n * 8 + kt * 4 + h];
        }
    }
    f32x4 acc[2][4];
#pragma unroll
    for (int nl = 0; nl < 2; ++nl)
#pragma unroll
        for (int mi = 0; mi < 4; ++mi) acc[nl][mi] = {0.f, 0.f, 0.f, 0.f};
#pragma unroll
    for (int mi = 0; mi < 4; ++mi) {
        int arow = (mi * 16 + cid) * 9;
        bf16x8 a0 = as_bf16x8(sa[arow + h]);        // kt=0
        bf16x8 a1 = as_bf16x8(sa[arow + 4 + h]);    // kt=1
#pragma unroll
        for (int nl = 0; nl < 2; ++nl) {
            acc[nl][mi] = __builtin_amdgcn_mfma_f32_16x16x32_bf16(a0, as_bf16x8(bh[nl][0]), acc[nl][mi], 0, 0, 0);
            acc[nl][mi] = __builtin_amdgcn_mfma_f32_16x16x32_bf16(a1, as_bf16x8(bh[nl][1]), acc[nl][mi], 0, 0, 0);
            acc[nl][mi] = __builtin_amdgcn_mfma_f32_16x16x32_bf16(a0, as_bf16x8(bl[nl][0]), acc[nl][mi], 0, 0, 0);
            acc[nl][mi] = __builtin_amdgcn_mfma_f32_16x16x32_bf16(a1, as_bf16x8(bl[nl][1]), acc[nl][mi], 0, 0, 0);
        }
    }
    // all sa reads done -> barrier, then reuse sa as spool (16 slots x 128 ch uint)
    __syncthreads();
    unsigned int* spool = (unsigned int*)sa;
    for (int i = t; i < 16 * 128; i += 256) spool[i] = 0u;
    __syncthreads();
    int g0 = sbatch[0], g63 = sbatch[63];
    // per-lane register run-length pool: 16 ascending nodes (mi*16 + h*4 + r), 2 chans
    int ch0 = (w * 2) * 16 + cid, ch1 = ch0 + 16;
    float bb0 = b3v[ch0], bb1 = b3v[ch1];
    int curg = sbatch[h * 4];   // first node of this lane (mi=0, r=0)
    float cm0 = 0.f, cm1 = 0.f;
#pragma unroll
    for (int mi = 0; mi < 4; ++mi) {
#pragma unroll
        for (int r = 0; r < 4; ++r) {
            int node_l = mi * 16 + h * 4 + r;
            int g = sbatch[node_l];
            if (g != curg) {
                int s = curg - g0 - 1;
                if (s >= 0 && curg < g63 && s < 16) {
                    atomicMax(&spool[s * 128 + ch0], __float_as_uint(cm0));
                    atomicMax(&spool[s * 128 + ch1], __float_as_uint(cm1));
                } else {
                    atomicMax(&pooled[curg * 128 + ch0], __float_as_uint(cm0));
                    atomicMax(&pooled[curg * 128 + ch1], __float_as_uint(cm1));
                }
                cm0 = 0.f; cm1 = 0.f;
                curg = g;
            }
            cm0 = fmaxf(cm0, fmaxf(acc[0][mi][r] + bb0, 0.f));
            cm1 = fmaxf(cm1, fmaxf(acc[1][mi][r] + bb1, 0.f));
        }
    }
    {
        int s = curg - g0 - 1;
        if (s >= 0 && curg < g63 && s < 16) {
            atomicMax(&spool[s * 128 + ch0], __float_as_uint(cm0));
            atomicMax(&spool[s * 128 + ch1], __float_as_uint(cm1));
        } else {
            atomicMax(&pooled[curg * 128 + ch0], __float_as_uint(cm0));
            atomicMax(&pooled[curg * 128 + ch1], __float_as_uint(cm1));
        }
    }
    __syncthreads();
    // interior graphs have this block as sole writer -> plain float4 stores
    {
        int s = t >> 4;              // slot 0..15
        int g = g0 + 1 + s;
        if (g < g63) {
            int ch = (t & 15) * 8;
            const float* spf = (const float*)spool;
            float4 v0 = *(const float4*)&spf[s * 128 + ch];
            float4 v1 = *(const float4*)&spf[s * 128 + ch + 4];
            float4* pf = (float4*)pooled;
            pf[g * 32 + (ch >> 2)] = v0;
            pf[g * 32 + (ch >> 2) + 1] = v1;
        }
    }
}

// ---- fused head: out = relu(pooled @ W1 + b1) @ W2 + b2, 8 graphs/block ----
__global__ __launch_bounds__(256) void k_head(const float* __restrict__ pooled,
                                              const float* __restrict__ W1v,
                                              const float* __restrict__ b1v,
                                              const float* __restrict__ W2v,
                                              const float* __restrict__ b2v,
                                              float* __restrict__ out) {
    __shared__ __align__(16) float sp[8 * 128];    // 4 KB
    __shared__ __align__(16) float smid[8 * 256];  // 8 KB
    __shared__ __align__(16) float sred[8 * 128];  // 4 KB
    int t = threadIdx.x;
    int base = blockIdx.x * 8;
    const float4* po4 = (const float4*)pooled;
    for (int i = t; i < 8 * 32; i += 256) ((float4*)sp)[i] = po4[base * 32 + i];
    __syncthreads();
    // phase 1: thread t owns lin1 output channel t (0..255)
    {
        float acc[8];
#pragma unroll
        for (int gl = 0; gl < 8; ++gl) acc[gl] = 0.f;
        const float4* sp4 = (const float4*)sp;
        for (int c4 = 0; c4 < 32; ++c4) {
            float w0 = W1v[(c4 * 4 + 0) * 256 + t];
            float w1 = W1v[(c4 * 4 + 1) * 256 + t];
            float w2 = W1v[(c4 * 4 + 2) * 256 + t];
            float w3 = W1v[(c4 * 4 + 3) * 256 + t];
#pragma unroll
            for (int gl = 0; gl < 8; ++gl) {
                float4 a = sp4[gl * 32 + c4];
                acc[gl] += a.x * w0 + a.y * w1 + a.z * w2 + a.w * w3;
            }
        }
        float bb = b1v[t];
#pragma unroll
        for (int gl = 0; gl < 8; ++gl) smid[gl * 256 + t] = fmaxf(acc[gl] + bb, 0.f);
    }
    __syncthreads();
    // phase 2: t = (half, k); each half sums its 128 c's; combine via LDS
    int k = t & 127, half = t >> 7;
    float acc2[8];
#pragma unroll
    for (int gl = 0; gl < 8; ++gl) acc2[gl] = 0.f;
    {
        const float* Wc = W2v + half * 128 * 128;    // rows half*128 .. +128
        const float4* sm4 = (const float4*)smid;
        for (int c4 = 0; c4 < 32; ++c4) {
            float w0 = Wc[(c4 * 4 + 0) * 128 + k];
            float w1 = Wc[(c4 * 4 + 1) * 128 + k];
            float w2 = Wc[(c4 * 4 + 2) * 128 + k];
            float w3 = Wc[(c4 * 4 + 3) * 128 + k];
#pragma unroll
            for (int gl = 0; gl < 8; ++gl) {
                float4 a = sm4[gl * 64 + half * 32 + c4];
                acc2[gl] += a.x * w0 + a.y * w1 + a.z * w2 + a.w * w3;
            }
        }
    }
    if (half == 1) {
#pragma unroll
        for (int gl = 0; gl < 8; ++gl) sred[gl * 128 + k] = acc2[gl];
    }
    __syncthreads();
    if (half == 0) {
        float bb = b2v[k];
#pragma unroll
        for (int gl = 0; gl < 8; ++gl)
            out[(base + gl) * 128 + k] = acc2[gl] + sred[gl * 128 + k] + bb;
    }
}

extern "C" void kernel_launch(void* const* d_in, const int* in_sizes, int n_in,
                              void* d_out, int out_size, void* d_ws, size_t ws_size,
                              hipStream_t stream) {
    (void)in_sizes; (void)n_in; (void)out_size; (void)ws_size;
    const float* x   = (const float*)d_in[0];
    const int* ei    = (const int*)d_in[1];
    const int* src = ei;
    const int* dst = ei + NE;
    const int* batch = (const int*)d_in[2];
    const float* nw  = (const float*)d_in[3];
    const float* nb  = (const float*)d_in[4];
    const float* W1  = (const float*)d_in[5];
    const float* b1  = (const float*)d_in[6];
    const float* W2  = (const float*)d_in[7];
    const float* b2  = (const float*)d_in[8];
    const float* W3  = (const float*)d_in[9];
    const float* b3  = (const float*)d_in[10];
    const float* l1W = (const float*)d_in[11];
    const float* l1b = (const float*)d_in[12];
    const float* l2W = (const float*)d_in[13];
    const float* l2b = (const float*)d_in[14];
    float* out = (float*)d_out;

    char* wsp = (char*)d_ws;
    int*   cnt      = (int*)wsp;   wsp += (size_t)NN * 4;        // becomes dis in place
    int*   rowstart = (int*)wsp;   wsp += (size_t)(NN + 1) * 4;
    int*   cursor   = (int*)wsp;   wsp += (size_t)NN * 4;
    int*   bsum     = (int*)wsp;   wsp += (size_t)NBS * 4;
    int*   bpre     = (int*)wsp;   wsp += (size_t)NBS * 4;
    int*   startg   = (int*)wsp;   wsp += (size_t)(NG + 1) * 4;
    int*   csr      = (int*)wsp;   wsp += (size_t)NE * 4;        // 3.2 MB
    wsp += ((256 - ((uintptr_t)wsp & 255)) & 255);
    unsigned short* w3hi = (unsigned short*)wsp; wsp += (size_t)128 * 64 * 2;  // 16 KB
    unsigned short* w3lo = (unsigned short*)wsp; wsp += (size_t)128 * 64 * 2;  // 16 KB
    float* scale   = (float*)wsp; wsp += (size_t)NG * 128 * 4;   // 4 MB
    float* shift   = (float*)wsp; wsp += (size_t)NG * 128 * 4;   // 4 MB
    float* pooled  = (float*)wsp; wsp += (size_t)NG * 128 * 4;   // 4 MB
    float* regionA = (float*)wsp; wsp += (size_t)NN * 64 * 4;    // p1|p2
    float* regionB = (float*)wsp; wsp += (size_t)NN * 64 * 4;    // p3h

    float* dis  = (float*)cnt;  // in-place after k_scanchunk
    float* p1   = regionA;
    float* p2   = regionA + (size_t)NN * 32;
    __hip_bfloat16* p3h = (__hip_bfloat16*)regionB;  // NN*64*2 B = 25.6 MB

    // CSR prep + starts + W3 split (independent work, one launch)
    hipMemsetAsync(cnt, 0, (size_t)NN * 4, stream);
    k_prep1<<<CNT_B + NBS + 32, 256, 0, stream>>>(dst, cnt, batch, startg, W3, w3hi, w3lo);
    k_blocksum<<<NBS, 256, 0, stream>>>(cnt, bsum);
    k_scanb<<<1, 1024, 0, stream>>>(bsum, bpre);
    k_scanchunk<<<NBS, 256, 0, stream>>>(cnt, bpre, rowstart, cursor);  // + dis, cursor
    // CSR fill standalone (no LDS -> full occupancy for the latency-bound scatter)
    k_fill<<<(NE + 255) / 256, 256, 0, stream>>>(src, dst, cursor, csr);

    // instance-norm stats (own kernel: clean HBM-bound pass)
    k_stats2<<<NG, 256, 0, stream>>>(x, startg, nw, nb, scale, shift);
    // layer 1
    k_conv1s<<<NN / 64, 256, 0, stream>>>(x, batch, scale, shift, W1, dis, p1);
    k_gather1<<<NN * 8 / 256, 256, 0, stream>>>(p1, rowstart, csr, dis, b1, p2);
    // layer 2 (fused gather+matmul, bf16 p3 store)
    k_conv2g<<<NN / 16, 256, 0, stream>>>(p2, rowstart, csr, dis, W2, b2, p3h);
    // layer 3 (fused bf16 gather + MFMA matmul + register pool)
    hipMemsetAsync(pooled, 0, (size_t)NG * 128 * 4, stream);
    k_conv3mg<<<NN / 64, 256, 0, stream>>>(p3h, rowstart, csr, dis, w3hi, w3lo, b3, batch,
                                           (unsigned int*)pooled);

    // fused head (lin1 + lin2)
    k_head<<<NG / 8, 256, 0, stream>>>(pooled, l1W, l1b, l2W, l2b, out);
}

// Round 18
// 449.205 us; speedup vs baseline: 1.1022x; 1.0572x over previous
//
#include <hip/hip_runtime.h>
#include <hip/hip_bf16.h>
#include <stdint.h>

#define NN 200000
#define NE 800000
#define FIN 128
#define NG 8000
#define EPSV 1e-5f
#define NBS ((NN + 255) / 256)   // 782 scan blocks
#define CNT_B (NE / 256)         // 3125 (exact)

typedef __attribute__((ext_vector_type(8))) short bf16x8;   // 8 bf16 = 4 VGPRs
typedef __attribute__((ext_vector_type(4))) float f32x4;    // MFMA C/D

static __device__ __forceinline__ bf16x8 as_bf16x8(uint4 u) {
    union { uint4 u; bf16x8 v; } c; c.u = u; return c.v;
}

// bf16 helpers: load-convert (exact) and pack with RNE
static __device__ __forceinline__ void u2f(uint4 v, float4& lo, float4& hi) {
    lo.x = __uint_as_float(v.x << 16); lo.y = __uint_as_float(v.x & 0xffff0000u);
    lo.z = __uint_as_float(v.y << 16); lo.w = __uint_as_float(v.y & 0xffff0000u);
    hi.x = __uint_as_float(v.z << 16); hi.y = __uint_as_float(v.z & 0xffff0000u);
    hi.z = __uint_as_float(v.w << 16); hi.w = __uint_as_float(v.w & 0xffff0000u);
}
static __device__ __forceinline__ unsigned int pk(float a, float b) {
    __hip_bfloat16 x = __float2bfloat16(a), y = __float2bfloat16(b);
    return (unsigned int)(*(unsigned short*)&x) | ((unsigned int)(*(unsigned short*)&y) << 16);
}
// split v into bf16 hi (RNE) and bf16 lo = bf16(v - float(hi))
static __device__ __forceinline__ void spl(float v, float& hf, float& lf) {
    __hip_bfloat16 h = __float2bfloat16(v);
    hf = __bfloat162float(h);
    lf = v - hf;
}

// ---- prep1: edge-count histogram | graph starts | W3 split | W2 split ----
__global__ __launch_bounds__(256) void k_prep1(const int* __restrict__ dst, int* __restrict__ cnt,
                                               const int* __restrict__ batch, int* __restrict__ startg,
                                               const float* __restrict__ W3,
                                               unsigned short* __restrict__ w3hi,
                                               unsigned short* __restrict__ w3lo,
                                               const float* __restrict__ W2,
                                               unsigned short* __restrict__ w2hi,
                                               unsigned short* __restrict__ w2lo) {
    int b = blockIdx.x, t = threadIdx.x;
    if (b < CNT_B) {
        int e = b * 256 + t;
        atomicAdd(&cnt[dst[e]], 1);
    } else if (b < CNT_B + NBS) {
        int n = (b - CNT_B) * 256 + t;
        if (n >= NN) return;
        int bb = batch[n];
        int prev = (n == 0) ? -1 : batch[n - 1];
        for (int g = prev + 1; g <= bb; ++g) startg[g] = n;
        if (n == NN - 1) {
            for (int g = bb + 1; g <= NG; ++g) startg[g] = NN;
        }
    } else if (b < CNT_B + NBS + 32) {
        int i = (b - CNT_B - NBS) * 256 + t;   // 8192 elems
        if (i >= 64 * 128) return;
        int n = i >> 6, k = i & 63;
        float w = W3[k * 128 + n];
        __hip_bfloat16 h = __float2bfloat16(w);
        float hf = __bfloat162float(h);
        __hip_bfloat16 l = __float2bfloat16(w - hf);
        w3hi[n * 64 + k] = *(unsigned short*)&h;
        w3lo[n * 64 + k] = *(unsigned short*)&l;
    } else {
        int i = (b - CNT_B - NBS - 32) * 256 + t;  // 2048 elems
        if (i >= 64 * 32) return;
        int ch = i >> 5, k = i & 31;
        float w = W2[k * 64 + ch];
        __hip_bfloat16 h = __float2bfloat16(w);
        float hf = __bfloat162float(h);
        __hip_bfloat16 l = __float2bfloat16(w - hf);
        w2hi[ch * 32 + k] = *(unsigned short*)&h;
        w2lo[ch * 32 + k] = *(unsigned short*)&l;
    }
}

// ---- per-256-chunk sums ----
__global__ void k_blocksum(const int* __restrict__ cnt, int* __restrict__ bsum) {
    __shared__ int sh[256];
    int b = blockIdx.x, t = threadIdx.x;
    int idx = b * 256 + t;
    sh[t] = (idx < NN) ? cnt[idx] : 0;
    __syncthreads();
    for (int o = 128; o > 0; o >>= 1) {
        if (t < o) sh[t] += sh[t + o];
        __syncthreads();
    }
    if (t == 0) bsum[b] = sh[0];
}

// ---- single-block scan of chunk sums -> exclusive prefixes ----
__global__ __launch_bounds__(1024) void k_scanb(const int* __restrict__ bsum, int* __restrict__ bpre) {
    __shared__ int sh[1024];
    int t = threadIdx.x;
    int v = (t < NBS) ? bsum[t] : 0;
    sh[t] = v;
    __syncthreads();
    for (int o = 1; o < 1024; o <<= 1) {
        int add = (t >= o) ? sh[t - o] : 0;
        __syncthreads();
        sh[t] += add;
        __syncthreads();
    }
    if (t < NBS) bpre[t] = sh[t] - v;  // exclusive
}

// ---- per-chunk scan + offset -> rowstart/cursor; dis = rsqrt(1+deg) in place ----
__global__ void k_scanchunk(int* __restrict__ cnt, const int* __restrict__ bpre,
                            int* __restrict__ rowstart, int* __restrict__ cursor) {
    __shared__ int sh[256];
    int b = blockIdx.x, t = threadIdx.x;
    int idx = b * 256 + t;
    int v = (idx < NN) ? cnt[idx] : 0;
    sh[t] = v;
    __syncthreads();
    for (int o = 1; o < 256; o <<= 1) {
        int add = (t >= o) ? sh[t - o] : 0;
        __syncthreads();
        sh[t] += add;
        __syncthreads();
    }
    if (idx < NN) {
        int rs = bpre[b] + sh[t] - v;
        rowstart[idx] = rs;
        cursor[idx] = rs;
        ((float*)cnt)[idx] = rsqrtf(1.0f + (float)v);  // cnt -> dis in place
    }
    if (idx == 0) rowstart[NN] = NE;
}

// ---- fill CSR: csr[pos] = src, bucketed by dst (standalone: no LDS, max occupancy) ----
__global__ void k_fill(const int* __restrict__ src, const int* __restrict__ dst,
                       int* __restrict__ cursor, int* __restrict__ csr) {
    int e = blockIdx.x * 256 + threadIdx.x;
    if (e < NE) {
        int pos = atomicAdd(&cursor[dst[e]], 1);
        csr[pos] = src[e];
    }
}

// ---- per-graph instance-norm stats, latency-tolerant: 8 node slots x 32 float4 lanes ----
__global__ __launch_bounds__(256) void k_stats2(const float* __restrict__ x,
                                                const int* __restrict__ startg,
                                                const float* __restrict__ nw,
                                                const float* __restrict__ nb,
                                                float* __restrict__ scale,
                                                float* __restrict__ shift) {
    __shared__ float4 rsum[256], rsq[256];
    int g = blockIdx.x;
    int s = startg[g], e = startg[g + 1];
    if (s == e) return;
    int t = threadIdx.x;
    int slot = t >> 5, c4 = t & 31;
    const float4* x4 = (const float4*)x;
    float4 sum = {0.f, 0.f, 0.f, 0.f}, sq = {0.f, 0.f, 0.f, 0.f};
    for (int n = s + slot; n < e; n += 8) {
        float4 v = x4[n * 32 + c4];
        sum.x += v.x; sum.y += v.y; sum.z += v.z; sum.w += v.w;
        sq.x += v.x * v.x; sq.y += v.y * v.y; sq.z += v.z * v.z; sq.w += v.w * v.w;
    }
    rsum[slot * 32 + c4] = sum;
    rsq[slot * 32 + c4] = sq;
    __syncthreads();
    if (t < 32) {
        float4 S = rsum[t], Q = rsq[t];
#pragma unroll
        for (int sl = 1; sl < 8; ++sl) {
            float4 a = rsum[sl * 32 + t], bq = rsq[sl * 32 + t];
            S.x += a.x; S.y += a.y; S.z += a.z; S.w += a.w;
            Q.x += bq.x; Q.y += bq.y; Q.z += bq.z; Q.w += bq.w;
        }
        float inv = 1.0f / (float)(e - s);
        float w = nw[0], bb = nb[0];
        float4 sc, sh;
        {
            float m = S.x * inv, v = fmaxf(Q.x * inv - m * m, 0.f);
            float is = rsqrtf(v + EPSV); sc.x = is * w; sh.x = bb - m * is * w;
        }
        {
            float m = S.y * inv, v = fmaxf(Q.y * inv - m * m, 0.f);
            float is = rsqrtf(v + EPSV); sc.y = is * w; sh.y = bb - m * is * w;
        }
        {
            float m = S.z * inv, v = fmaxf(Q.z * inv - m * m, 0.f);
            float is = rsqrtf(v + EPSV); sc.z = is * w; sh.z = bb - m * is * w;
        }
        {
            float m = S.w * inv, v = fmaxf(Q.w * inv - m * m, 0.f);
            float is = rsqrtf(v + EPSV); sc.w = is * w; sh.w = bb - m * is * w;
        }
        ((float4*)scale)[g * 32 + t] = sc;
        ((float4*)shift)[g * 32 + t] = sh;
    }
}

// ---- conv1, lane-per-node: 64 nodes/block, lane=node, wave owns 8 output chans. ----
__global__ __launch_bounds__(256) void k_conv1s(const float* __restrict__ x,
                                                const int* __restrict__ batch,
                                                const float* __restrict__ scale,
                                                const float* __restrict__ shift,
                                                const float* __restrict__ W1,
                                                const float* __restrict__ dis,
                                                float* __restrict__ p1) {
    __shared__ float4 sx4[64 * 33];   // row stride 33 f4 (132 dwords = 4 mod 32: conflict-free)
    int t = threadIdx.x;
    int base = blockIdx.x * 64;       // NN % 64 == 0
    const float4* x4 = (const float4*)x;
    const float4* sc4 = (const float4*)scale;
    const float4* sh4 = (const float4*)shift;
    for (int i = t; i < 64 * 32; i += 256) {
        int nl = i >> 5, c4 = i & 31;
        int n = base + nl;
        int g = batch[n];
        float4 xv = x4[n * 32 + c4];
        float4 sc = sc4[g * 32 + c4];
        float4 sh = sh4[g * 32 + c4];
        float4 r;
        r.x = fmaf(xv.x, sc.x, sh.x);
        r.y = fmaf(xv.y, sc.y, sh.y);
        r.z = fmaf(xv.z, sc.z, sh.z);
        r.w = fmaf(xv.w, sc.w, sh.w);
        sx4[nl * 33 + c4] = r;
    }
    __syncthreads();
    int lane = t & 63;
    int kq = __builtin_amdgcn_readfirstlane(t >> 6) * 2;  // f4 column index (k0 = kq*4)
    const float4* W4 = (const float4*)W1;                 // [128 rows][8 f4]
    const float4* arow = &sx4[lane * 33];
    float4 acc0 = {0.f, 0.f, 0.f, 0.f}, acc1 = {0.f, 0.f, 0.f, 0.f};
#pragma unroll 4
    for (int c4 = 0; c4 < 32; ++c4) {
        float4 a = arow[c4];
        int rb = c4 * 32 + kq;        // rows 4*c4 .. 4*c4+3, cols kq,kq+1
        float4 wA0 = W4[rb +  0], wA1 = W4[rb +  1];
        float4 wB0 = W4[rb +  8], wB1 = W4[rb +  9];
        float4 wC0 = W4[rb + 16], wC1 = W4[rb + 17];
        float4 wD0 = W4[rb + 24], wD1 = W4[rb + 25];
        acc0.x += a.x * wA0.x + a.y * wB0.x + a.z * wC0.x + a.w * wD0.x;
        acc0.y += a.x * wA0.y + a.y * wB0.y + a.z * wC0.y + a.w * wD0.y;
        acc0.z += a.x * wA0.z + a.y * wB0.z + a.z * wC0.z + a.w * wD0.z;
        acc0.w += a.x * wA0.w + a.y * wB0.w + a.z * wC0.w + a.w * wD0.w;
        acc1.x += a.x * wA1.x + a.y * wB1.x + a.z * wC1.x + a.w * wD1.x;
        acc1.y += a.x * wA1.y + a.y * wB1.y + a.z * wC1.y + a.w * wD1.y;
        acc1.z += a.x * wA1.z + a.y * wB1.z + a.z * wC1.z + a.w * wD1.z;
        acc1.w += a.x * wA1.w + a.y * wB1.w + a.z * wC1.w + a.w * wD1.w;
    }
    int n = base + lane;
    float d = dis[n];
    float4 r0, r1;
    r0.x = acc0.x * d; r0.y = acc0.y * d; r0.z = acc0.z * d; r0.w = acc0.w * d;
    r1.x = acc1.x * d; r1.y = acc1.y * d; r1.z = acc1.z * d; r1.w = acc1.w * d;
    ((float4*)p1)[n * 8 + kq] = r0;
    ((float4*)p1)[n * 8 + kq + 1] = r1;
}

// ---- gather1 (C=32, float4) + conv1 epilogue: p2 = relu(dis*(self+neigh)+b1)*dis ----
__global__ __launch_bounds__(256) void k_gather1(const float* __restrict__ p1,
                                                 const int* __restrict__ rowstart,
                                                 const int* __restrict__ csr,
                                                 const float* __restrict__ dis,
                                                 const float* __restrict__ b1,
                                                 float* __restrict__ p2) {
    int tid = blockIdx.x * 256 + threadIdx.x;  // NN*8 threads
    int n = tid >> 3, c4 = tid & 7;
    const float4* p1_4 = (const float4*)p1;
    int s = rowstart[n], e = rowstart[n + 1];
    float4 agg = p1_4[n * 8 + c4];  // self-loop (p = h*dis already)
    int j = s;
    for (; j + 1 < e; j += 2) {
        float4 v0 = p1_4[csr[j] * 8 + c4];
        float4 v1 = p1_4[csr[j + 1] * 8 + c4];
        agg.x += v0.x + v1.x; agg.y += v0.y + v1.y;
        agg.z += v0.z + v1.z; agg.w += v0.w + v1.w;
    }
    if (j < e) {
        float4 v = p1_4[csr[j] * 8 + c4];
        agg.x += v.x; agg.y += v.y; agg.z += v.z; agg.w += v.w;
    }
    float d = dis[n];
    float4 bb = ((const float4*)b1)[c4];
    float4 r;
    r.x = fmaxf(d * agg.x + bb.x, 0.f) * d;
    r.y = fmaxf(d * agg.y + bb.y, 0.f) * d;
    r.z = fmaxf(d * agg.z + bb.z, 0.f) * d;
    r.w = fmaxf(d * agg.w + bb.w, 0.f) * d;
    ((float4*)p2)[n * 8 + c4] = r;
}

// ---- conv2 via MFMA: 64 nodes/block; gather p2 (fp32) -> hi/lo bf16 split in LDS;
//      A,W both split -> 4 exact cross-products = fp32-grade result (no new rounding).
//      K=32 = one 16x16x32 step; wave w owns ch-tile w; 16 MFMAs/wave. ----
__global__ __launch_bounds__(256) void k_conv2m(const float* __restrict__ p2,
                                                const int* __restrict__ rowstart,
                                                const int* __restrict__ csr,
                                                const float* __restrict__ dis,
                                                const unsigned short* __restrict__ w2hi,
                                                const unsigned short* __restrict__ w2lo,
                                                const float* __restrict__ b2v,
                                                __hip_bfloat16* __restrict__ p3h) {
    __shared__ uint2 sah[64 * 10];   // [node][granule*2+half], row stride 10 uint2 = 5 KB
    __shared__ uint2 sal[64 * 10];   // 5 KB
    __shared__ float sdis[64];
    int t = threadIdx.x;
    int base = blockIdx.x * 64;
    if (t < 64) sdis[t] = dis[base + t];
    const float4* p2_4 = (const float4*)p2;
    for (int i = t; i < 64 * 8; i += 256) {
        int nl = i >> 3, c4 = i & 7;
        int n = base + nl;
        int s = rowstart[n], e = rowstart[n + 1];
        float4 agg = p2_4[n * 8 + c4];   // self
        int j = s;
        for (; j + 1 < e; j += 2) {
            float4 v0 = p2_4[csr[j] * 8 + c4];
            float4 v1 = p2_4[csr[j + 1] * 8 + c4];
            agg.x += v0.x + v1.x; agg.y += v0.y + v1.y;
            agg.z += v0.z + v1.z; agg.w += v0.w + v1.w;
        }
        if (j < e) {
            float4 v = p2_4[csr[j] * 8 + c4];
            agg.x += v.x; agg.y += v.y; agg.z += v.z; agg.w += v.w;
        }
        float d = dis[n];
        float ax = d * agg.x, ay = d * agg.y, az = d * agg.z, aw = d * agg.w;
        float hx, lx, hy, ly, hz, lz, hw, lw;
        spl(ax, hx, lx); spl(ay, hy, ly); spl(az, hz, lz); spl(aw, hw, lw);
        uint2 hh, ll;
        hh.x = pk(hx, hy); hh.y = pk(hz, hw);
        ll.x = pk(lx, ly); ll.y = pk(lz, lw);
        sah[nl * 10 + c4] = hh;      // (c4>>1)*2 + (c4&1) == c4
        sal[nl * 10 + c4] = ll;
    }
    __syncthreads();
    int lane = t & 63, w = t >> 6;
    int h = lane >> 4;        // k-granule 0..3 (k = h*8 + j)
    int cid = lane & 15;      // col within 16
    int ch = w * 16 + cid;    // output channel 0..63
    const uint4* WHq = (const uint4*)w2hi;   // [64 ch][4 granules]
    const uint4* WLq = (const uint4*)w2lo;
    bf16x8 bh = as_bf16x8(WHq[ch * 4 + h]);
    bf16x8 bl = as_bf16x8(WLq[ch * 4 + h]);
    const uint4* sah4 = (const uint4*)sah;   // row stride 5 uint4
    const uint4* sal4 = (const uint4*)sal;
    f32x4 acc[4];
#pragma unroll
    for (int mi = 0; mi < 4; ++mi) acc[mi] = {0.f, 0.f, 0.f, 0.f};
#pragma unroll
    for (int mi = 0; mi < 4; ++mi) {
        int arow = (mi * 16 + cid) * 5 + h;
        bf16x8 ah = as_bf16x8(sah4[arow]);
        bf16x8 al = as_bf16x8(sal4[arow]);
        acc[mi] = __builtin_amdgcn_mfma_f32_16x16x32_bf16(ah, bh, acc[mi], 0, 0, 0);
        acc[mi] = __builtin_amdgcn_mfma_f32_16x16x32_bf16(ah, bl, acc[mi], 0, 0, 0);
        acc[mi] = __builtin_amdgcn_mfma_f32_16x16x32_bf16(al, bh, acc[mi], 0, 0, 0);
        acc[mi] = __builtin_amdgcn_mfma_f32_16x16x32_bf16(al, bl, acc[mi], 0, 0, 0);
    }
    float bb = b2v[ch];
#pragma unroll
    for (int mi = 0; mi < 4; ++mi) {
#pragma unroll
        for (int r = 0; r < 4; ++r) {
            int nloc = mi * 16 + h * 4 + r;
            float hv = fmaxf(acc[mi][r] + bb, 0.f);
            p3h[(size_t)(base + nloc) * 64 + ch] = __float2bfloat16(hv * sdis[nloc]);
        }
    }
}

// ---- conv3: fused edge-gather -> LDS -> MFMA -> register run-length pool. ----
__global__ __launch_bounds__(256) void k_conv3mg(const __hip_bfloat16* __restrict__ p3h,
                                                 const int* __restrict__ rowstart,
                                                 const int* __restrict__ csr,
                                                 const float* __restrict__ dis,
                                                 const unsigned short* __restrict__ w3hi,
                                                 const unsigned short* __restrict__ w3lo,
                                                 const float* __restrict__ b3v,
                                                 const int* __restrict__ batch,
                                                 unsigned int* __restrict__ pooled) {
    __shared__ uint4 sa[64 * 9];     // 9.2 KB; reused as spool (8 KB) after MFMA
    __shared__ int sbatch[64];
    int t = threadIdx.x;
    int base = blockIdx.x * 64;
    if (t < 64) sbatch[t] = batch[base + t];
    const uint4* p3q = (const uint4*)p3h;
    // fused gather3: 512 (node, c8) tasks, 2 per thread
    for (int i = t; i < 64 * 8; i += 256) {
        int nl = i >> 3, c8 = i & 7;
        int n = base + nl;
        int s = rowstart[n], e = rowstart[n + 1];
        float4 alo, ahi;
        u2f(p3q[n * 8 + c8], alo, ahi);  // self
        int j = s;
        for (; j + 1 < e; j += 2) {
            float4 l0, h0, l1, h1;
            u2f(p3q[csr[j] * 8 + c8], l0, h0);
            u2f(p3q[csr[j + 1] * 8 + c8], l1, h1);
            alo.x += l0.x + l1.x; alo.y += l0.y + l1.y;
            alo.z += l0.z + l1.z; alo.w += l0.w + l1.w;
            ahi.x += h0.x + h1.x; ahi.y += h0.y + h1.y;
            ahi.z += h0.z + h1.z; ahi.w += h0.w + h1.w;
        }
        if (j < e) {
            float4 l0, h0;
            u2f(p3q[csr[j] * 8 + c8], l0, h0);
            alo.x += l0.x; alo.y += l0.y; alo.z += l0.z; alo.w += l0.w;
            ahi.x += h0.x; ahi.y += h0.y; ahi.z += h0.z; ahi.w += h0.w;
        }
        float d = dis[n];
        uint4 o;
        o.x = pk(d * alo.x, d * alo.y);
        o.y = pk(d * alo.z, d * alo.w);
        o.z = pk(d * ahi.x, d * ahi.y);
        o.w = pk(d * ahi.z, d * ahi.w);
        sa[nl * 9 + c8] = o;
    }
    __syncthreads();
    int lane = t & 63, w = t >> 6;
    int h = lane >> 4;        // k-group 0..3 (k = kt*32 + h*8 + j)
    int cid = lane & 15;      // row (A) / col (B,C) within 16
    const uint4* WHq = (const uint4*)w3hi;   // [128 ch][8 granules]
    const uint4* WLq = (const uint4*)w3lo;
    uint4 bh[2][2], bl[2][2];
#pragma unroll
    for (int nl = 0; nl < 2; ++nl) {
        int n = (w * 2 + nl) * 16 + cid;
#pragma unroll
        for (int kt = 0; kt < 2; ++kt) {
            bh[nl][kt] = WHq[n * 8 + kt * 4 + h];
            bl[nl][kt] = WLq[n * 8 + kt * 4 + h];
        }
    }
    f32x4 acc[2][4];
#pragma unroll
    for (int nl = 0; nl < 2; ++nl)
#pragma unroll
        for (int mi = 0; mi < 4; ++mi) acc[nl][mi] = {0.f, 0.f, 0.f, 0.f};
#pragma unroll
    for (int mi = 0; mi < 4; ++mi) {
        int arow = (mi * 16 + cid) * 9;
        bf16x8 a0 = as_bf16x8(sa[arow + h]);        // kt=0
        bf16x8 a1 = as_bf16x8(sa[arow + 4 + h]);    // kt=1
#pragma unroll
        for (int nl = 0; nl < 2; ++nl) {
            acc[nl][mi] = __builtin_amdgcn_mfma_f32_16x16x32_bf16(a0, as_bf16x8(bh[nl][0]), acc[nl][mi], 0, 0, 0);
            acc[nl][mi] = __builtin_amdgcn_mfma_f32_16x16x32_bf16(a1, as_bf16x8(bh[nl][1]), acc[nl][mi], 0, 0, 0);
            acc[nl][mi] = __builtin_amdgcn_mfma_f32_16x16x32_bf16(a0, as_bf16x8(bl[nl][0]), acc[nl][mi], 0, 0, 0);
            acc[nl][mi] = __builtin_amdgcn_mfma_f32_16x16x32_bf16(a1, as_bf16x8(bl[nl][1]), acc[nl][mi], 0, 0, 0);
        }
    }
    // all sa reads done -> barrier, then reuse sa as spool (16 slots x 128 ch uint)
    __syncthreads();
    unsigned int* spool = (unsigned int*)sa;
    for (int i = t; i < 16 * 128; i += 256) spool[i] = 0u;
    __syncthreads();
    int g0 = sbatch[0], g63 = sbatch[63];
    // per-lane register run-length pool: 16 ascending nodes (mi*16 + h*4 + r), 2 chans
    int ch0 = (w * 2) * 16 + cid, ch1 = ch0 + 16;
    float bb0 = b3v[ch0], bb1 = b3v[ch1];
    int curg = sbatch[h * 4];   // first node of this lane (mi=0, r=0)
    float cm0 = 0.f, cm1 = 0.f;
#pragma unroll
    for (int mi = 0; mi < 4; ++mi) {
#pragma unroll
        for (int r = 0; r < 4; ++r) {
            int node_l = mi * 16 + h * 4 + r;
            int g = sbatch[node_l];
            if (g != curg) {
                int s = curg - g0 - 1;
                if (s >= 0 && curg < g63 && s < 16) {
                    atomicMax(&spool[s * 128 + ch0], __float_as_uint(cm0));
                    atomicMax(&spool[s * 128 + ch1], __float_as_uint(cm1));
                } else {
                    atomicMax(&pooled[curg * 128 + ch0], __float_as_uint(cm0));
                    atomicMax(&pooled[curg * 128 + ch1], __float_as_uint(cm1));
                }
                cm0 = 0.f; cm1 = 0.f;
                curg = g;
            }
            cm0 = fmaxf(cm0, fmaxf(acc[0][mi][r] + bb0, 0.f));
            cm1 = fmaxf(cm1, fmaxf(acc[1][mi][r] + bb1, 0.f));
        }
    }
    {
        int s = curg - g0 - 1;
        if (s >= 0 && curg < g63 && s < 16) {
            atomicMax(&spool[s * 128 + ch0], __float_as_uint(cm0));
            atomicMax(&spool[s * 128 + ch1], __float_as_uint(cm1));
        } else {
            atomicMax(&pooled[curg * 128 + ch0], __float_as_uint(cm0));
            atomicMax(&pooled[curg * 128 + ch1], __float_as_uint(cm1));
        }
    }
    __syncthreads();
    // interior graphs have this block as sole writer -> plain float4 stores
    {
        int s = t >> 4;              // slot 0..15
        int g = g0 + 1 + s;
        if (g < g63) {
            int ch = (t & 15) * 8;
            const float* spf = (const float*)spool;
            float4 v0 = *(const float4*)&spf[s * 128 + ch];
            float4 v1 = *(const float4*)&spf[s * 128 + ch + 4];
            float4* pf = (float4*)pooled;
            pf[g * 32 + (ch >> 2)] = v0;
            pf[g * 32 + (ch >> 2) + 1] = v1;
        }
    }
}

// ---- fused head: out = relu(pooled @ W1 + b1) @ W2 + b2, 8 graphs/block ----
__global__ __launch_bounds__(256) void k_head(const float* __restrict__ pooled,
                                              const float* __restrict__ W1v,
                                              const float* __restrict__ b1v,
                                              const float* __restrict__ W2v,
                                              const float* __restrict__ b2v,
                                              float* __restrict__ out) {
    __shared__ __align__(16) float sp[8 * 128];    // 4 KB
    __shared__ __align__(16) float smid[8 * 256];  // 8 KB
    __shared__ __align__(16) float sred[8 * 128];  // 4 KB
    int t = threadIdx.x;
    int base = blockIdx.x * 8;
    const float4* po4 = (const float4*)pooled;
    for (int i = t; i < 8 * 32; i += 256) ((float4*)sp)[i] = po4[base * 32 + i];
    __syncthreads();
    // phase 1: thread t owns lin1 output channel t (0..255)
    {
        float acc[8];
#pragma unroll
        for (int gl = 0; gl < 8; ++gl) acc[gl] = 0.f;
        const float4* sp4 = (const float4*)sp;
        for (int c4 = 0; c4 < 32; ++c4) {
            float w0 = W1v[(c4 * 4 + 0) * 256 + t];
            float w1 = W1v[(c4 * 4 + 1) * 256 + t];
            float w2 = W1v[(c4 * 4 + 2) * 256 + t];
            float w3 = W1v[(c4 * 4 + 3) * 256 + t];
#pragma unroll
            for (int gl = 0; gl < 8; ++gl) {
                float4 a = sp4[gl * 32 + c4];
                acc[gl] += a.x * w0 + a.y * w1 + a.z * w2 + a.w * w3;
            }
        }
        float bb = b1v[t];
#pragma unroll
        for (int gl = 0; gl < 8; ++gl) smid[gl * 256 + t] = fmaxf(acc[gl] + bb, 0.f);
    }
    __syncthreads();
    // phase 2: t = (half, k); each half sums its 128 c's; combine via LDS
    int k = t & 127, half = t >> 7;
    float acc2[8];
#pragma unroll
    for (int gl = 0; gl < 8; ++gl) acc2[gl] = 0.f;
    {
        const float* Wc = W2v + half * 128 * 128;    // rows half*128 .. +128
        const float4* sm4 = (const float4*)smid;
        for (int c4 = 0; c4 < 32; ++c4) {
            float w0 = Wc[(c4 * 4 + 0) * 128 + k];
            float w1 = Wc[(c4 * 4 + 1) * 128 + k];
            float w2 = Wc[(c4 * 4 + 2) * 128 + k];
            float w3 = Wc[(c4 * 4 + 3) * 128 + k];
#pragma unroll
            for (int gl = 0; gl < 8; ++gl) {
                float4 a = sm4[gl * 64 + half * 32 + c4];
                acc2[gl] += a.x * w0 + a.y * w1 + a.z * w2 + a.w * w3;
            }
        }
    }
    if (half == 1) {
#pragma unroll
        for (int gl = 0; gl < 8; ++gl) sred[gl * 128 + k] = acc2[gl];
    }
    __syncthreads();
    if (half == 0) {
        float bb = b2v[k];
#pragma unroll
        for (int gl = 0; gl < 8; ++gl)
            out[(base + gl) * 128 + k] = acc2[gl] + sred[gl * 128 + k] + bb;
    }
}

extern "C" void kernel_launch(void* const* d_in, const int* in_sizes, int n_in,
                              void* d_out, int out_size, void* d_ws, size_t ws_size,
                              hipStream_t stream) {
    (void)in_sizes; (void)n_in; (void)out_size; (void)ws_size;
    const float* x   = (const float*)d_in[0];
    const int* ei    = (const int*)d_in[1];
    const int* src = ei;
    const int* dst = ei + NE;
    const int* batch = (const int*)d_in[2];
    const float* nw  = (const float*)d_in[3];
    const float* nb  = (const float*)d_in[4];
    const float* W1  = (const float*)d_in[5];
    const float* b1  = (const float*)d_in[6];
    const float* W2  = (const float*)d_in[7];
    const float* b2  = (const float*)d_in[8];
    const float* W3  = (const float*)d_in[9];
    const float* b3  = (const float*)d_in[10];
    const float* l1W = (const float*)d_in[11];
    const float* l1b = (const float*)d_in[12];
    const float* l2W = (const float*)d_in[13];
    const float* l2b = (const float*)d_in[14];
    float* out = (float*)d_out;

    char* wsp = (char*)d_ws;
    int*   cnt      = (int*)wsp;   wsp += (size_t)NN * 4;        // becomes dis in place
    int*   rowstart = (int*)wsp;   wsp += (size_t)(NN + 1) * 4;
    int*   cursor   = (int*)wsp;   wsp += (size_t)NN * 4;
    int*   bsum     = (int*)wsp;   wsp += (size_t)NBS * 4;
    int*   bpre     = (int*)wsp;   wsp += (size_t)NBS * 4;
    int*   startg   = (int*)wsp;   wsp += (size_t)(NG + 1) * 4;
    int*   csr      = (int*)wsp;   wsp += (size_t)NE * 4;        // 3.2 MB
    wsp += ((256 - ((uintptr_t)wsp & 255)) & 255);
    unsigned short* w3hi = (unsigned short*)wsp; wsp += (size_t)128 * 64 * 2;  // 16 KB
    unsigned short* w3lo = (unsigned short*)wsp; wsp += (size_t)128 * 64 * 2;  // 16 KB
    unsigned short* w2hi = (unsigned short*)wsp; wsp += (size_t)64 * 32 * 2;   // 4 KB
    unsigned short* w2lo = (unsigned short*)wsp; wsp += (size_t)64 * 32 * 2;   // 4 KB
    float* scale   = (float*)wsp; wsp += (size_t)NG * 128 * 4;   // 4 MB
    float* shift   = (float*)wsp; wsp += (size_t)NG * 128 * 4;   // 4 MB
    float* pooled  = (float*)wsp; wsp += (size_t)NG * 128 * 4;   // 4 MB
    float* regionA = (float*)wsp; wsp += (size_t)NN * 64 * 4;    // p1|p2
    float* regionB = (float*)wsp; wsp += (size_t)NN * 64 * 4;    // p3h

    float* dis  = (float*)cnt;  // in-place after k_scanchunk
    float* p1   = regionA;
    float* p2   = regionA + (size_t)NN * 32;
    __hip_bfloat16* p3h = (__hip_bfloat16*)regionB;  // NN*64*2 B = 25.6 MB

    // CSR prep + starts + W3/W2 splits (independent work, one launch)
    hipMemsetAsync(cnt, 0, (size_t)NN * 4, stream);
    k_prep1<<<CNT_B + NBS + 40, 256, 0, stream>>>(dst, cnt, batch, startg,
                                                  W3, w3hi, w3lo, W2, w2hi, w2lo);
    k_blocksum<<<NBS, 256, 0, stream>>>(cnt, bsum);
    k_scanb<<<1, 1024, 0, stream>>>(bsum, bpre);
    k_scanchunk<<<NBS, 256, 0, stream>>>(cnt, bpre, rowstart, cursor);  // + dis, cursor
    // CSR fill standalone (no LDS -> full occupancy for the latency-bound scatter)
    k_fill<<<(NE + 255) / 256, 256, 0, stream>>>(src, dst, cursor, csr);

    // instance-norm stats (own kernel: clean HBM-bound pass)
    k_stats2<<<NG, 256, 0, stream>>>(x, startg, nw, nb, scale, shift);
    // layer 1
    k_conv1s<<<NN / 64, 256, 0, stream>>>(x, batch, scale, shift, W1, dis, p1);
    k_gather1<<<NN * 8 / 256, 256, 0, stream>>>(p1, rowstart, csr, dis, b1, p2);
    // layer 2 (fused gather + MFMA matmul via exact hi/lo splits)
    k_conv2m<<<NN / 64, 256, 0, stream>>>(p2, rowstart, csr, dis, w2hi, w2lo, b2, p3h);
    // layer 3 (fused bf16 gather + MFMA matmul + register pool)
    hipMemsetAsync(pooled, 0, (size_t)NG * 128 * 4, stream);
    k_conv3mg<<<NN / 64, 256, 0, stream>>>(p3h, rowstart, csr, dis, w3hi, w3lo, b3, batch,
                                           (unsigned int*)pooled);

    // fused head (lin1 + lin2)
    k_head<<<NG / 8, 256, 0, stream>>>(pooled, l1W, l1b, l2W, l2b, out);
}